// Round 1
// baseline (327.413 us; speedup 1.0000x reference)
//
#include <hip/hip_runtime.h>
#include <hip/hip_bf16.h>
#include <math.h>

#define S 2048
#define DM 1024
#define QIN 512
#define HI 16
#define DI 64
#define NH 8
#define TOPK 128
#define LN_EPS 1e-5f

__device__ __forceinline__ float wave_sum(float v){
#pragma unroll
  for (int o = 32; o; o >>= 1) v += __shfl_xor(v, o);
  return v;
}
__device__ __forceinline__ float wave_max(float v){
#pragma unroll
  for (int o = 32; o; o >>= 1) v = fmaxf(v, __shfl_xor(v, o));
  return v;
}

// ---------------- kernel 1: split-K partial GEMM  x(2048x1024) @ [w_k | w_weights](1024x80) ----------------
__global__ __launch_bounds__(256) void k_part(const float* __restrict__ x,
                                              const float* __restrict__ wk,
                                              const float* __restrict__ ww,
                                              float* __restrict__ part){
  const int kp = blockIdx.x;   // 0..3 (K split)
  const int bm = blockIdx.y;   // 0..31
  const int t  = threadIdx.x;
  const int m0 = bm * 64;
  __shared__ float As[32][68];  // [k][m]
  __shared__ float Bs[32][84];  // [k][n]
  const int tm = (t & 15) * 4;
  const int tn = (t >> 4) * 5;
  float acc[4][5];
#pragma unroll
  for (int i = 0; i < 4; i++)
#pragma unroll
    for (int j = 0; j < 5; j++) acc[i][j] = 0.f;

  for (int kb = 0; kb < 8; ++kb){
    const int k0 = kp * 256 + kb * 32;
#pragma unroll
    for (int i = 0; i < 2; i++){
      int u = t + i * 256;
      int m = u >> 3, c4 = u & 7;
      float4 a = *(const float4*)&x[(size_t)(m0 + m) * DM + k0 + c4 * 4];
      As[c4*4+0][m] = a.x; As[c4*4+1][m] = a.y; As[c4*4+2][m] = a.z; As[c4*4+3][m] = a.w;
    }
#pragma unroll
    for (int i = 0; i < 10; i++){
      int u = t + i * 256;
      int kk = u / 80, nn = u % 80;
      float val = (nn < 64) ? wk[(size_t)(k0 + kk) * 64 + nn]
                            : ww[(size_t)(k0 + kk) * 16 + (nn - 64)];
      Bs[kk][nn] = val;
    }
    __syncthreads();
#pragma unroll
    for (int k = 0; k < 32; ++k){
      float4 a = *(const float4*)&As[k][tm];
      float av[4] = {a.x, a.y, a.z, a.w};
      float bb[5];
#pragma unroll
      for (int j = 0; j < 5; j++) bb[j] = Bs[k][tn + j];
#pragma unroll
      for (int i = 0; i < 4; i++)
#pragma unroll
        for (int j = 0; j < 5; j++) acc[i][j] = fmaf(av[i], bb[j], acc[i][j]);
    }
    __syncthreads();
  }
  float* dst = part + (size_t)kp * S * 80;
#pragma unroll
  for (int i = 0; i < 4; i++)
#pragma unroll
    for (int j = 0; j < 5; j++)
      dst[(size_t)(m0 + tm + i) * 80 + tn + j] = acc[i][j];
}

// ---------------- kernel 2: reduce split-K partials, LayerNorm(ki), scale wgt ----------------
__global__ __launch_bounds__(64) void k_lnw(const float* __restrict__ part,
                                            const float* __restrict__ g,
                                            const float* __restrict__ b,
                                            float* __restrict__ ki,
                                            float* __restrict__ wgt){
  const int s = blockIdx.x, l = threadIdx.x;
  float kv = 0.f;
#pragma unroll
  for (int p = 0; p < 4; p++) kv += part[(size_t)p * S * 80 + (size_t)s * 80 + l];
  float wv = 0.f;
  if (l < 16){
#pragma unroll
    for (int p = 0; p < 4; p++) wv += part[(size_t)p * S * 80 + (size_t)s * 80 + 64 + l];
  }
  float mu = wave_sum(kv) * (1.f / 64.f);
  float d  = kv - mu;
  float var = wave_sum(d * d) * (1.f / 64.f);
  float o = d * (1.f / sqrtf(var + LN_EPS)) * g[l] + b[l];
  ki[(size_t)s * 64 + l] = o;
  if (l < 16) wgt[(size_t)s * 16 + l] = wv * 0.25f;   // HI^-0.5
}

// ---------------- kernel 3: qi = q_input(2048x512) @ w_q(512x1024) ----------------
__global__ __launch_bounds__(256) void k_qi(const float* __restrict__ qin,
                                            const float* __restrict__ wq,
                                            float* __restrict__ qi){
  const int bn = blockIdx.x, bm = blockIdx.y;
  const int t = threadIdx.x;
  const int m0 = bm * 64, n0 = bn * 64;
  __shared__ float As[32][68];
  __shared__ float Bs[32][68];
  const int tm = (t & 15) * 4;
  const int tn = (t >> 4) * 4;
  float acc[4][4] = {};
  for (int kb = 0; kb < 16; ++kb){
    const int k0 = kb * 32;
#pragma unroll
    for (int i = 0; i < 2; i++){
      int u = t + i * 256;
      int m = u >> 3, c4 = u & 7;
      float4 a = *(const float4*)&qin[(size_t)(m0 + m) * QIN + k0 + c4 * 4];
      As[c4*4+0][m] = a.x; As[c4*4+1][m] = a.y; As[c4*4+2][m] = a.z; As[c4*4+3][m] = a.w;
    }
#pragma unroll
    for (int i = 0; i < 2; i++){
      int u = t + i * 256;
      int kk = u >> 4, n4 = u & 15;
      float4 bv = *(const float4*)&wq[(size_t)(k0 + kk) * 1024 + n0 + n4 * 4];
      *(float4*)&Bs[kk][n4 * 4] = bv;
    }
    __syncthreads();
#pragma unroll
    for (int k = 0; k < 32; ++k){
      float4 a = *(const float4*)&As[k][tm];
      float4 bv = *(const float4*)&Bs[k][tn];
      float av[4] = {a.x, a.y, a.z, a.w}, bb[4] = {bv.x, bv.y, bv.z, bv.w};
#pragma unroll
      for (int i = 0; i < 4; i++)
#pragma unroll
        for (int j = 0; j < 4; j++) acc[i][j] = fmaf(av[i], bb[j], acc[i][j]);
    }
    __syncthreads();
  }
#pragma unroll
  for (int i = 0; i < 4; i++)
#pragma unroll
    for (int j = 0; j < 4; j++)
      qi[(size_t)(m0 + tm + i) * 1024 + n0 + tn + j] = acc[i][j];
}

// ---------------- kernel 4: q_eff[s,d] = DI^-0.5 * sum_h wgt[s,h]*qi[s,h*64+d] ----------------
__global__ __launch_bounds__(256) void k_qeff(const float* __restrict__ qi,
                                              const float* __restrict__ wgt,
                                              float* __restrict__ qe){
  const int id = blockIdx.x * 256 + threadIdx.x;  // S*64 total
  const int s = id >> 6, d = id & 63;
  float acc = 0.f;
#pragma unroll
  for (int h = 0; h < 16; h++)
    acc = fmaf(wgt[(size_t)s * 16 + h], qi[(size_t)s * 1024 + h * 64 + d], acc);
  qe[(size_t)s * 64 + d] = acc * 0.125f;   // DI^-0.5
}

// ---------------- kernel 5: scores[i,j] = q_eff[i] . ki[j]  (lower-triangular tiles only) ----------------
__global__ __launch_bounds__(256) void k_scores(const float* __restrict__ qe,
                                                const float* __restrict__ ki,
                                                float* __restrict__ sc){
  const int bj = blockIdx.x, bi = blockIdx.y;
  if (bj > bi) return;
  const int t = threadIdx.x;
  const int i0 = bi * 64, j0 = bj * 64;
  __shared__ float Qs[64][68];  // [d][i]
  __shared__ float Ks[64][68];  // [d][j]
#pragma unroll
  for (int u0 = 0; u0 < 4; ++u0){
    int u = t + u0 * 256;
    int r = u >> 4, d4 = u & 15;
    float4 a = *(const float4*)&qe[(size_t)(i0 + r) * 64 + d4 * 4];
    Qs[d4*4+0][r] = a.x; Qs[d4*4+1][r] = a.y; Qs[d4*4+2][r] = a.z; Qs[d4*4+3][r] = a.w;
    float4 b = *(const float4*)&ki[(size_t)(j0 + r) * 64 + d4 * 4];
    Ks[d4*4+0][r] = b.x; Ks[d4*4+1][r] = b.y; Ks[d4*4+2][r] = b.z; Ks[d4*4+3][r] = b.w;
  }
  __syncthreads();
  const int tm = (t & 15) * 4, tn = (t >> 4) * 4;
  float acc[4][4] = {};
#pragma unroll
  for (int d = 0; d < 64; ++d){
    float4 a = *(const float4*)&Qs[d][tm];
    float4 b = *(const float4*)&Ks[d][tn];
    float av[4] = {a.x, a.y, a.z, a.w}, bb[4] = {b.x, b.y, b.z, b.w};
#pragma unroll
    for (int i = 0; i < 4; i++)
#pragma unroll
      for (int j = 0; j < 4; j++) acc[i][j] = fmaf(av[i], bb[j], acc[i][j]);
  }
#pragma unroll
  for (int i = 0; i < 4; i++)
#pragma unroll
    for (int j = 0; j < 4; j++)
      sc[(size_t)(i0 + tm + i) * S + j0 + tn + j] = acc[i][j];
}

// ---------------- kernel 6: per-row causal top-128 via 4-pass radix select ----------------
__global__ __launch_bounds__(256) void k_topk(const float* __restrict__ sc,
                                              int* __restrict__ idx,
                                              int* __restrict__ cnt){
  const int i = blockIdx.x, t = threadIdx.x;
  const int n = i + 1;           // valid causal candidates
  int* outr = idx + (size_t)i * TOPK;
  if (n <= TOPK){
    for (int m = t; m < n; m += 256) outr[m] = m;
    if (t == 0) cnt[i] = n;
    return;
  }
  __shared__ unsigned int keys[S];
  __shared__ int tl[S];
  __shared__ int hist[256];
  __shared__ int s_b, s_above, s_gt, s_eq;
  for (int j = t; j < n; j += 256){
    unsigned int u = __float_as_uint(sc[(size_t)i * S + j]);
    keys[j] = (u & 0x80000000u) ? ~u : (u | 0x80000000u);   // order-preserving key
  }
  unsigned int prefix = 0;
  int rem = TOPK;
  for (int p = 3; p >= 0; --p){
    const int sh = p * 8;
    __syncthreads();
    hist[t] = 0;
    if (t < 0) {}      // (256 threads == 256 bins)
    __syncthreads();
    const unsigned int himask = (p == 3) ? 0u : (0xFFFFFFFFu << (sh + 8));
    for (int j = t; j < n; j += 256){
      unsigned int kk = keys[j];
      if ((kk & himask) == (prefix & himask)) atomicAdd(&hist[(kk >> sh) & 255], 1);
    }
    __syncthreads();
    if (t == 0){
      int cum = 0, b = 255;
      for (int d = 255; d >= 0; --d){
        if (cum + hist[d] >= rem){ b = d; break; }
        cum += hist[d];
      }
      s_b = b; s_above = cum;
    }
    __syncthreads();
    prefix |= ((unsigned int)s_b) << sh;
    rem -= s_above;
  }
  if (t == 0){ s_gt = 0; s_eq = 0; }
  __syncthreads();
  for (int j = t; j < n; j += 256){
    unsigned int kk = keys[j];
    if (kk > prefix){ int p = atomicAdd(&s_gt, 1); outr[p] = j; }
    else if (kk == prefix){ int p = atomicAdd(&s_eq, 1); tl[p] = j; }
  }
  __syncthreads();
  const int base = s_gt;          // == TOPK - rem
  if (s_eq == rem){
    for (int m = t; m < rem; m += 256) outr[base + m] = tl[m];
  } else if (t == 0){             // rare exact-tie path: lowest indices first
    int taken = 0;
    for (int j = 0; j < n && taken < rem; ++j)
      if (keys[j] == prefix) outr[base + taken++] = j;
  }
  if (t == 0) cnt[i] = TOPK;
}

// ---------------- kernel 7: gathered sparse attention ----------------
__global__ __launch_bounds__(256) void k_attn(const float* __restrict__ q,
                                              const float* __restrict__ k,
                                              const float* __restrict__ v,
                                              const int* __restrict__ idx,
                                              const int* __restrict__ cnt,
                                              float* __restrict__ out){
  const int i = blockIdx.x;
  const int w = threadIdx.x >> 6, l = threadIdx.x & 63;
  const int n = cnt[i];
  const int* irow = idx + (size_t)i * TOPK;
  __shared__ float att[4][2][128];
  const int h0 = w * 2, h1 = w * 2 + 1;
  const int i0 = (l < n) ? irow[l] : 0;
  const int i1 = (64 + l < n) ? irow[64 + l] : 0;
  const float q0 = q[((size_t)i * NH + h0) * 64 + l] * 0.125f;  // DQK^-0.5
  const float q1 = q[((size_t)i * NH + h1) * 64 + l] * 0.125f;
  for (int j = 0; j < n; ++j){
    int ij = __shfl((j < 64) ? i0 : i1, j & 63);
    float k0v = k[((size_t)ij * NH + h0) * 64 + l];
    float k1v = k[((size_t)ij * NH + h1) * 64 + l];
    float d0 = q0 * k0v, d1 = q1 * k1v;
#pragma unroll
    for (int o = 32; o; o >>= 1){ d0 += __shfl_xor(d0, o); d1 += __shfl_xor(d1, o); }
    if (l == 0){ att[w][0][j] = d0; att[w][1][j] = d1; }
  }
  __syncthreads();
#pragma unroll
  for (int hh = 0; hh < 2; ++hh){
    float a0 = (l < n) ? att[w][hh][l] : -1e30f;
    float a1 = (64 + l < n) ? att[w][hh][64 + l] : -1e30f;
    float m = wave_max(fmaxf(a0, a1));
    float e0 = (l < n) ? __expf(a0 - m) : 0.f;
    float e1 = (64 + l < n) ? __expf(a1 - m) : 0.f;
    float ssum = wave_sum(e0 + e1);
    float inv = 1.f / ssum;
    att[w][hh][l] = e0 * inv;
    att[w][hh][64 + l] = e1 * inv;
  }
  __syncthreads();
  float o0 = 0.f, o1 = 0.f;
  for (int j = 0; j < n; ++j){
    int ij = __shfl((j < 64) ? i0 : i1, j & 63);
    float p0 = att[w][0][j], p1 = att[w][1][j];
    o0 = fmaf(p0, v[((size_t)ij * NH + h0) * 64 + l], o0);
    o1 = fmaf(p1, v[((size_t)ij * NH + h1) * 64 + l], o1);
  }
  out[((size_t)i * NH + h0) * 64 + l] = o0;
  out[((size_t)i * NH + h1) * 64 + l] = o1;
}

extern "C" void kernel_launch(void* const* d_in, const int* in_sizes, int n_in,
                              void* d_out, int out_size, void* d_ws, size_t ws_size,
                              hipStream_t stream){
  const float* x   = (const float*)d_in[0];
  const float* qin = (const float*)d_in[1];
  const float* q   = (const float*)d_in[2];
  const float* k   = (const float*)d_in[3];
  const float* v   = (const float*)d_in[4];
  const float* wq  = (const float*)d_in[5];
  const float* wk  = (const float*)d_in[6];
  const float* lng = (const float*)d_in[7];
  const float* lnb = (const float*)d_in[8];
  const float* ww  = (const float*)d_in[9];
  float* out = (float*)d_out;

  float* ws   = (float*)d_ws;
  float* part = ws;                  // 4*2048*80   = 655360
  float* ki   = ws + 655360;         // 2048*64     = 131072
  float* wgt  = ws + 786432;         // 2048*16     = 32768
  float* qi   = ws + 819200;         // 2048*1024   = 2097152
  float* qe   = ws + 2916352;        // 2048*64     = 131072
  float* sc   = ws + 3047424;        // 2048*2048   = 4194304
  int*   idx  = (int*)(ws + 7241728);// 2048*128 ints
  int*   cnt  = (int*)(ws + 7503872);// 2048 ints

  hipLaunchKernelGGL(k_part,   dim3(4, 32),  dim3(256), 0, stream, x, wk, ww, part);
  hipLaunchKernelGGL(k_lnw,    dim3(2048),   dim3(64),  0, stream, part, lng, lnb, ki, wgt);
  hipLaunchKernelGGL(k_qi,     dim3(16, 32), dim3(256), 0, stream, qin, wq, qi);
  hipLaunchKernelGGL(k_qeff,   dim3(512),    dim3(256), 0, stream, qi, wgt, qe);
  hipLaunchKernelGGL(k_scores, dim3(32, 32), dim3(256), 0, stream, qe, ki, sc);
  hipLaunchKernelGGL(k_topk,   dim3(2048),   dim3(256), 0, stream, sc, idx, cnt);
  hipLaunchKernelGGL(k_attn,   dim3(2048),   dim3(256), 0, stream, q, k, v, idx, cnt, out);
}

// Round 2
// 281.270 us; speedup vs baseline: 1.1640x; 1.1640x over previous
//
#include <hip/hip_runtime.h>
#include <hip/hip_bf16.h>
#include <math.h>

#define S 2048
#define DM 1024
#define QIN 512
#define HI 16
#define DI 64
#define NH 8
#define TOPK 128
#define LN_EPS 1e-5f

__device__ __forceinline__ float wave_sum(float v){
#pragma unroll
  for (int o = 32; o; o >>= 1) v += __shfl_xor(v, o);
  return v;
}
__device__ __forceinline__ float wave_max(float v){
#pragma unroll
  for (int o = 32; o; o >>= 1) v = fmaxf(v, __shfl_xor(v, o));
  return v;
}

// ---------------- kernel 1: split-K partial GEMM  x(2048x1024) @ [w_k | w_weights](1024x80) ----------------
__global__ __launch_bounds__(256) void k_part(const float* __restrict__ x,
                                              const float* __restrict__ wk,
                                              const float* __restrict__ ww,
                                              float* __restrict__ part){
  const int kp = blockIdx.x;   // 0..3 (K split)
  const int bm = blockIdx.y;   // 0..31
  const int t  = threadIdx.x;
  const int m0 = bm * 64;
  __shared__ float As[32][68];  // [k][m]
  __shared__ float Bs[32][84];  // [k][n]
  const int tm = (t & 15) * 4;
  const int tn = (t >> 4) * 5;
  float acc[4][5];
#pragma unroll
  for (int i = 0; i < 4; i++)
#pragma unroll
    for (int j = 0; j < 5; j++) acc[i][j] = 0.f;

  for (int kb = 0; kb < 8; ++kb){
    const int k0 = kp * 256 + kb * 32;
#pragma unroll
    for (int i = 0; i < 2; i++){
      int u = t + i * 256;
      int m = u >> 3, c4 = u & 7;
      float4 a = *(const float4*)&x[(size_t)(m0 + m) * DM + k0 + c4 * 4];
      As[c4*4+0][m] = a.x; As[c4*4+1][m] = a.y; As[c4*4+2][m] = a.z; As[c4*4+3][m] = a.w;
    }
#pragma unroll
    for (int i = 0; i < 10; i++){
      int u = t + i * 256;
      int kk = u / 80, nn = u % 80;
      float val = (nn < 64) ? wk[(size_t)(k0 + kk) * 64 + nn]
                            : ww[(size_t)(k0 + kk) * 16 + (nn - 64)];
      Bs[kk][nn] = val;
    }
    __syncthreads();
#pragma unroll
    for (int k = 0; k < 32; ++k){
      float4 a = *(const float4*)&As[k][tm];
      float av[4] = {a.x, a.y, a.z, a.w};
      float bb[5];
#pragma unroll
      for (int j = 0; j < 5; j++) bb[j] = Bs[k][tn + j];
#pragma unroll
      for (int i = 0; i < 4; i++)
#pragma unroll
        for (int j = 0; j < 5; j++) acc[i][j] = fmaf(av[i], bb[j], acc[i][j]);
    }
    __syncthreads();
  }
  float* dst = part + (size_t)kp * S * 80;
#pragma unroll
  for (int i = 0; i < 4; i++)
#pragma unroll
    for (int j = 0; j < 5; j++)
      dst[(size_t)(m0 + tm + i) * 80 + tn + j] = acc[i][j];
}

// ---------------- kernel 2: reduce split-K partials, LayerNorm(ki), scale wgt ----------------
__global__ __launch_bounds__(64) void k_lnw(const float* __restrict__ part,
                                            const float* __restrict__ g,
                                            const float* __restrict__ b,
                                            float* __restrict__ ki,
                                            float* __restrict__ wgt){
  const int s = blockIdx.x, l = threadIdx.x;
  float kv = 0.f;
#pragma unroll
  for (int p = 0; p < 4; p++) kv += part[(size_t)p * S * 80 + (size_t)s * 80 + l];
  float wv = 0.f;
  if (l < 16){
#pragma unroll
    for (int p = 0; p < 4; p++) wv += part[(size_t)p * S * 80 + (size_t)s * 80 + 64 + l];
  }
  float mu = wave_sum(kv) * (1.f / 64.f);
  float d  = kv - mu;
  float var = wave_sum(d * d) * (1.f / 64.f);
  float o = d * (1.f / sqrtf(var + LN_EPS)) * g[l] + b[l];
  ki[(size_t)s * 64 + l] = o;
  if (l < 16) wgt[(size_t)s * 16 + l] = wv * 0.25f;   // HI^-0.5
}

// ---------------- kernel 3: qi = q_input(2048x512) @ w_q(512x1024) ----------------
__global__ __launch_bounds__(256) void k_qi(const float* __restrict__ qin,
                                            const float* __restrict__ wq,
                                            float* __restrict__ qi){
  const int bn = blockIdx.x, bm = blockIdx.y;
  const int t = threadIdx.x;
  const int m0 = bm * 64, n0 = bn * 64;
  __shared__ float As[32][68];
  __shared__ float Bs[32][68];
  const int tm = (t & 15) * 4;
  const int tn = (t >> 4) * 4;
  float acc[4][4] = {};
  for (int kb = 0; kb < 16; ++kb){
    const int k0 = kb * 32;
#pragma unroll
    for (int i = 0; i < 2; i++){
      int u = t + i * 256;
      int m = u >> 3, c4 = u & 7;
      float4 a = *(const float4*)&qin[(size_t)(m0 + m) * QIN + k0 + c4 * 4];
      As[c4*4+0][m] = a.x; As[c4*4+1][m] = a.y; As[c4*4+2][m] = a.z; As[c4*4+3][m] = a.w;
    }
#pragma unroll
    for (int i = 0; i < 2; i++){
      int u = t + i * 256;
      int kk = u >> 4, n4 = u & 15;
      float4 bv = *(const float4*)&wq[(size_t)(k0 + kk) * 1024 + n0 + n4 * 4];
      *(float4*)&Bs[kk][n4 * 4] = bv;
    }
    __syncthreads();
#pragma unroll
    for (int k = 0; k < 32; ++k){
      float4 a = *(const float4*)&As[k][tm];
      float4 bv = *(const float4*)&Bs[k][tn];
      float av[4] = {a.x, a.y, a.z, a.w}, bb[4] = {bv.x, bv.y, bv.z, bv.w};
#pragma unroll
      for (int i = 0; i < 4; i++)
#pragma unroll
        for (int j = 0; j < 4; j++) acc[i][j] = fmaf(av[i], bb[j], acc[i][j]);
    }
    __syncthreads();
  }
#pragma unroll
  for (int i = 0; i < 4; i++)
#pragma unroll
    for (int j = 0; j < 4; j++)
      qi[(size_t)(m0 + tm + i) * 1024 + n0 + tn + j] = acc[i][j];
}

// ---------------- kernel 4: q_eff[s,d] = DI^-0.5 * sum_h wgt[s,h]*qi[s,h*64+d] ----------------
__global__ __launch_bounds__(256) void k_qeff(const float* __restrict__ qi,
                                              const float* __restrict__ wgt,
                                              float* __restrict__ qe){
  const int id = blockIdx.x * 256 + threadIdx.x;  // S*64 total
  const int s = id >> 6, d = id & 63;
  float acc = 0.f;
#pragma unroll
  for (int h = 0; h < 16; h++)
    acc = fmaf(wgt[(size_t)s * 16 + h], qi[(size_t)s * 1024 + h * 64 + d], acc);
  qe[(size_t)s * 64 + d] = acc * 0.125f;   // DI^-0.5
}

// ---------------- kernel 5: scores[i,j] = q_eff[i] . ki[j]  (lower-triangular tiles only) ----------------
__global__ __launch_bounds__(256) void k_scores(const float* __restrict__ qe,
                                                const float* __restrict__ ki,
                                                float* __restrict__ sc){
  const int bj = blockIdx.x, bi = blockIdx.y;
  if (bj > bi) return;
  const int t = threadIdx.x;
  const int i0 = bi * 64, j0 = bj * 64;
  __shared__ float Qs[64][68];  // [d][i]
  __shared__ float Ks[64][68];  // [d][j]
#pragma unroll
  for (int u0 = 0; u0 < 4; ++u0){
    int u = t + u0 * 256;
    int r = u >> 4, d4 = u & 15;
    float4 a = *(const float4*)&qe[(size_t)(i0 + r) * 64 + d4 * 4];
    Qs[d4*4+0][r] = a.x; Qs[d4*4+1][r] = a.y; Qs[d4*4+2][r] = a.z; Qs[d4*4+3][r] = a.w;
    float4 b = *(const float4*)&ki[(size_t)(j0 + r) * 64 + d4 * 4];
    Ks[d4*4+0][r] = b.x; Ks[d4*4+1][r] = b.y; Ks[d4*4+2][r] = b.z; Ks[d4*4+3][r] = b.w;
  }
  __syncthreads();
  const int tm = (t & 15) * 4, tn = (t >> 4) * 4;
  float acc[4][4] = {};
#pragma unroll
  for (int d = 0; d < 64; ++d){
    float4 a = *(const float4*)&Qs[d][tm];
    float4 b = *(const float4*)&Ks[d][tn];
    float av[4] = {a.x, a.y, a.z, a.w}, bb[4] = {b.x, b.y, b.z, b.w};
#pragma unroll
    for (int i = 0; i < 4; i++)
#pragma unroll
      for (int j = 0; j < 4; j++) acc[i][j] = fmaf(av[i], bb[j], acc[i][j]);
  }
#pragma unroll
  for (int i = 0; i < 4; i++)
#pragma unroll
    for (int j = 0; j < 4; j++)
      sc[(size_t)(i0 + tm + i) * S + j0 + tn + j] = acc[i][j];
}

// ---------------- kernel 6: per-row causal top-128 via 4-pass radix select ----------------
__global__ __launch_bounds__(256) void k_topk(const float* __restrict__ sc,
                                              int* __restrict__ idx,
                                              int* __restrict__ cnt){
  const int i = blockIdx.x, t = threadIdx.x;
  const int n = i + 1;           // valid causal candidates
  int* outr = idx + (size_t)i * TOPK;
  if (n <= TOPK){
    for (int m = t; m < n; m += 256) outr[m] = m;
    if (t == 0) cnt[i] = n;
    return;
  }
  __shared__ unsigned int keys[S];
  __shared__ int tl[S];
  __shared__ int hist[256];
  __shared__ int s_b, s_above, s_gt, s_eq;
  for (int j = t; j < n; j += 256){
    unsigned int u = __float_as_uint(sc[(size_t)i * S + j]);
    keys[j] = (u & 0x80000000u) ? ~u : (u | 0x80000000u);   // order-preserving key
  }
  unsigned int prefix = 0;
  int rem = TOPK;
  for (int p = 3; p >= 0; --p){
    const int sh = p * 8;
    __syncthreads();
    hist[t] = 0;
    __syncthreads();
    const unsigned int himask = (p == 3) ? 0u : (0xFFFFFFFFu << (sh + 8));
    for (int j = t; j < n; j += 256){
      unsigned int kk = keys[j];
      if ((kk & himask) == (prefix & himask)) atomicAdd(&hist[(kk >> sh) & 255], 1);
    }
    __syncthreads();
    if (t == 0){
      int cum = 0, b = 255;
      for (int d = 255; d >= 0; --d){
        if (cum + hist[d] >= rem){ b = d; break; }
        cum += hist[d];
      }
      s_b = b; s_above = cum;
    }
    __syncthreads();
    prefix |= ((unsigned int)s_b) << sh;
    rem -= s_above;
  }
  if (t == 0){ s_gt = 0; s_eq = 0; }
  __syncthreads();
  for (int j = t; j < n; j += 256){
    unsigned int kk = keys[j];
    if (kk > prefix){ int p = atomicAdd(&s_gt, 1); outr[p] = j; }
    else if (kk == prefix){ int p = atomicAdd(&s_eq, 1); tl[p] = j; }
  }
  __syncthreads();
  const int base = s_gt;          // == TOPK - rem
  if (s_eq == rem){
    for (int m = t; m < rem; m += 256) outr[base + m] = tl[m];
  } else if (t == 0){             // rare exact-tie path: lowest indices first
    int taken = 0;
    for (int j = 0; j < n && taken < rem; ++j)
      if (keys[j] == prefix) outr[base + taken++] = j;
  }
  if (t == 0) cnt[i] = TOPK;
}

// ---------------- kernel 7: gathered sparse attention (key-parallel QK, coalesced PV) ----------------
__global__ __launch_bounds__(256) void k_attn(const float* __restrict__ q,
                                              const float* __restrict__ k,
                                              const float* __restrict__ v,
                                              const int* __restrict__ idx,
                                              const int* __restrict__ cnt,
                                              float* __restrict__ out){
  const int i = blockIdx.x;
  const int t = threadIdx.x;
  const int w = t >> 6, l = t & 63;
  const int n = cnt[i];
  const int* irow = idx + (size_t)i * TOPK;

  __shared__ int   sidx[TOPK];
  __shared__ float sq[NH][64];
  __shared__ float sp[NH][TOPK];

  if (t < TOPK) sidx[t] = (t < n) ? irow[t] : 0;
  for (int u = t; u < NH * 64; u += 256)
    sq[u >> 6][u & 63] = q[(size_t)i * (NH * 64) + u] * 0.125f;   // DQK^-0.5
  __syncthreads();

  const int h0 = w * 2, h1 = h0 + 1;

  // ---- QK: lane l owns keys j=l and j=l+64 (both heads of this wave) ----
  const int ij0 = sidx[l];
  const int ij1 = sidx[l + 64];
  const float* kb0 = k + (size_t)ij0 * (NH * 64);
  const float* kb1 = k + (size_t)ij1 * (NH * 64);
  float a00 = 0.f, a01 = 0.f, a10 = 0.f, a11 = 0.f;  // a[key][head]
#pragma unroll
  for (int d4 = 0; d4 < 16; ++d4){
    float4 qa = *(const float4*)&sq[h0][d4 * 4];
    float4 qb = *(const float4*)&sq[h1][d4 * 4];
    float4 k00 = *(const float4*)&kb0[h0 * 64 + d4 * 4];
    float4 k01 = *(const float4*)&kb0[h1 * 64 + d4 * 4];
    float4 k10 = *(const float4*)&kb1[h0 * 64 + d4 * 4];
    float4 k11 = *(const float4*)&kb1[h1 * 64 + d4 * 4];
    a00 = fmaf(qa.x, k00.x, fmaf(qa.y, k00.y, fmaf(qa.z, k00.z, fmaf(qa.w, k00.w, a00))));
    a01 = fmaf(qb.x, k01.x, fmaf(qb.y, k01.y, fmaf(qb.z, k01.z, fmaf(qb.w, k01.w, a01))));
    a10 = fmaf(qa.x, k10.x, fmaf(qa.y, k10.y, fmaf(qa.z, k10.z, fmaf(qa.w, k10.w, a10))));
    a11 = fmaf(qb.x, k11.x, fmaf(qb.y, k11.y, fmaf(qb.z, k11.z, fmaf(qb.w, k11.w, a11))));
  }
  const bool v0 = (l < n), v1 = (l + 64 < n);
  // ---- softmax per head across the wave (2 entries per lane) ----
  {
    float s0 = v0 ? a00 : -1e30f, s1 = v1 ? a10 : -1e30f;
    float m = wave_max(fmaxf(s0, s1));
    float e0 = v0 ? __expf(s0 - m) : 0.f;
    float e1 = v1 ? __expf(s1 - m) : 0.f;
    float inv = 1.f / wave_sum(e0 + e1);
    sp[h0][l] = e0 * inv;
    sp[h0][l + 64] = e1 * inv;
  }
  {
    float s0 = v0 ? a01 : -1e30f, s1 = v1 ? a11 : -1e30f;
    float m = wave_max(fmaxf(s0, s1));
    float e0 = v0 ? __expf(s0 - m) : 0.f;
    float e1 = v1 ? __expf(s1 - m) : 0.f;
    float inv = 1.f / wave_sum(e0 + e1);
    sp[h1][l] = e0 * inv;
    sp[h1][l + 64] = e1 * inv;
  }
  __syncthreads();

  // ---- PV: lane l = output dim; coalesced 256B reads per key row ----
  float o0 = 0.f, o1 = 0.f;
#pragma unroll 4
  for (int j = 0; j < n; ++j){
    const float* vb = v + (size_t)sidx[j] * (NH * 64);
    o0 = fmaf(sp[h0][j], vb[h0 * 64 + l], o0);
    o1 = fmaf(sp[h1][j], vb[h1 * 64 + l], o1);
  }
  out[((size_t)i * NH + h0) * 64 + l] = o0;
  out[((size_t)i * NH + h1) * 64 + l] = o1;
}

extern "C" void kernel_launch(void* const* d_in, const int* in_sizes, int n_in,
                              void* d_out, int out_size, void* d_ws, size_t ws_size,
                              hipStream_t stream){
  const float* x   = (const float*)d_in[0];
  const float* qin = (const float*)d_in[1];
  const float* q   = (const float*)d_in[2];
  const float* k   = (const float*)d_in[3];
  const float* v   = (const float*)d_in[4];
  const float* wq  = (const float*)d_in[5];
  const float* wk  = (const float*)d_in[6];
  const float* lng = (const float*)d_in[7];
  const float* lnb = (const float*)d_in[8];
  const float* ww  = (const float*)d_in[9];
  float* out = (float*)d_out;

  float* ws   = (float*)d_ws;
  float* part = ws;                  // 4*2048*80   = 655360
  float* ki   = ws + 655360;         // 2048*64     = 131072
  float* wgt  = ws + 786432;         // 2048*16     = 32768
  float* qi   = ws + 819200;         // 2048*1024   = 2097152
  float* qe   = ws + 2916352;        // 2048*64     = 131072
  float* sc   = ws + 3047424;        // 2048*2048   = 4194304
  int*   idx  = (int*)(ws + 7241728);// 2048*128 ints
  int*   cnt  = (int*)(ws + 7503872);// 2048 ints

  hipLaunchKernelGGL(k_part,   dim3(4, 32),  dim3(256), 0, stream, x, wk, ww, part);
  hipLaunchKernelGGL(k_lnw,    dim3(2048),   dim3(64),  0, stream, part, lng, lnb, ki, wgt);
  hipLaunchKernelGGL(k_qi,     dim3(16, 32), dim3(256), 0, stream, qin, wq, qi);
  hipLaunchKernelGGL(k_qeff,   dim3(512),    dim3(256), 0, stream, qi, wgt, qe);
  hipLaunchKernelGGL(k_scores, dim3(32, 32), dim3(256), 0, stream, qe, ki, sc);
  hipLaunchKernelGGL(k_topk,   dim3(2048),   dim3(256), 0, stream, sc, idx, cnt);
  hipLaunchKernelGGL(k_attn,   dim3(2048),   dim3(256), 0, stream, q, k, v, idx, cnt, out);
}

// Round 3
// 172.953 us; speedup vs baseline: 1.8931x; 1.6263x over previous
//
#include <hip/hip_runtime.h>
#include <hip/hip_bf16.h>
#include <math.h>

#define S 2048
#define DM 1024
#define QIN 512
#define HI 16
#define DI 64
#define NH 8
#define TOPK 128
#define LN_EPS 1e-5f

__device__ __forceinline__ float wave_sum(float v){
#pragma unroll
  for (int o = 32; o; o >>= 1) v += __shfl_xor(v, o);
  return v;
}
__device__ __forceinline__ float wave_max(float v){
#pragma unroll
  for (int o = 32; o; o >>= 1) v = fmaxf(v, __shfl_xor(v, o));
  return v;
}

// ---------------- kernel 1: split-K partial GEMM  x(2048x1024) @ [w_k | w_weights](1024x80) ----------------
__global__ __launch_bounds__(256) void k_part(const float* __restrict__ x,
                                              const float* __restrict__ wk,
                                              const float* __restrict__ ww,
                                              float* __restrict__ part){
  const int kp = blockIdx.x;   // 0..3 (K split)
  const int bm = blockIdx.y;   // 0..31
  const int t  = threadIdx.x;
  const int m0 = bm * 64;
  __shared__ float As[32][68];  // [k][m]
  __shared__ float Bs[32][84];  // [k][n]
  const int tm = (t & 15) * 4;
  const int tn = (t >> 4) * 5;
  float acc[4][5];
#pragma unroll
  for (int i = 0; i < 4; i++)
#pragma unroll
    for (int j = 0; j < 5; j++) acc[i][j] = 0.f;

  for (int kb = 0; kb < 8; ++kb){
    const int k0 = kp * 256 + kb * 32;
#pragma unroll
    for (int i = 0; i < 2; i++){
      int u = t + i * 256;
      int m = u >> 3, c4 = u & 7;
      float4 a = *(const float4*)&x[(size_t)(m0 + m) * DM + k0 + c4 * 4];
      As[c4*4+0][m] = a.x; As[c4*4+1][m] = a.y; As[c4*4+2][m] = a.z; As[c4*4+3][m] = a.w;
    }
#pragma unroll
    for (int i = 0; i < 10; i++){
      int u = t + i * 256;
      int kk = u / 80, nn = u % 80;
      float val = (nn < 64) ? wk[(size_t)(k0 + kk) * 64 + nn]
                            : ww[(size_t)(k0 + kk) * 16 + (nn - 64)];
      Bs[kk][nn] = val;
    }
    __syncthreads();
#pragma unroll
    for (int k = 0; k < 32; ++k){
      float4 a = *(const float4*)&As[k][tm];
      float av[4] = {a.x, a.y, a.z, a.w};
      float bb[5];
#pragma unroll
      for (int j = 0; j < 5; j++) bb[j] = Bs[k][tn + j];
#pragma unroll
      for (int i = 0; i < 4; i++)
#pragma unroll
        for (int j = 0; j < 5; j++) acc[i][j] = fmaf(av[i], bb[j], acc[i][j]);
    }
    __syncthreads();
  }
  float* dst = part + (size_t)kp * S * 80;
#pragma unroll
  for (int i = 0; i < 4; i++)
#pragma unroll
    for (int j = 0; j < 5; j++)
      dst[(size_t)(m0 + tm + i) * 80 + tn + j] = acc[i][j];
}

// ---------------- kernel 2: reduce split-K partials, LayerNorm(ki), scale wgt ----------------
__global__ __launch_bounds__(64) void k_lnw(const float* __restrict__ part,
                                            const float* __restrict__ g,
                                            const float* __restrict__ b,
                                            float* __restrict__ ki,
                                            float* __restrict__ wgt){
  const int s = blockIdx.x, l = threadIdx.x;
  float kv = 0.f;
#pragma unroll
  for (int p = 0; p < 4; p++) kv += part[(size_t)p * S * 80 + (size_t)s * 80 + l];
  float wv = 0.f;
  if (l < 16){
#pragma unroll
    for (int p = 0; p < 4; p++) wv += part[(size_t)p * S * 80 + (size_t)s * 80 + 64 + l];
  }
  float mu = wave_sum(kv) * (1.f / 64.f);
  float d  = kv - mu;
  float var = wave_sum(d * d) * (1.f / 64.f);
  float o = d * (1.f / sqrtf(var + LN_EPS)) * g[l] + b[l];
  ki[(size_t)s * 64 + l] = o;
  if (l < 16) wgt[(size_t)s * 16 + l] = wv * 0.25f;   // HI^-0.5
}

// ---------------- kernel 3: qi = q_input(2048x512) @ w_q(512x1024) ----------------
__global__ __launch_bounds__(256) void k_qi(const float* __restrict__ qin,
                                            const float* __restrict__ wq,
                                            float* __restrict__ qi){
  const int bn = blockIdx.x, bm = blockIdx.y;
  const int t = threadIdx.x;
  const int m0 = bm * 64, n0 = bn * 64;
  __shared__ float As[32][68];
  __shared__ float Bs[32][68];
  const int tm = (t & 15) * 4;
  const int tn = (t >> 4) * 4;
  float acc[4][4] = {};
  for (int kb = 0; kb < 16; ++kb){
    const int k0 = kb * 32;
#pragma unroll
    for (int i = 0; i < 2; i++){
      int u = t + i * 256;
      int m = u >> 3, c4 = u & 7;
      float4 a = *(const float4*)&qin[(size_t)(m0 + m) * QIN + k0 + c4 * 4];
      As[c4*4+0][m] = a.x; As[c4*4+1][m] = a.y; As[c4*4+2][m] = a.z; As[c4*4+3][m] = a.w;
    }
#pragma unroll
    for (int i = 0; i < 2; i++){
      int u = t + i * 256;
      int kk = u >> 4, n4 = u & 15;
      float4 bv = *(const float4*)&wq[(size_t)(k0 + kk) * 1024 + n0 + n4 * 4];
      *(float4*)&Bs[kk][n4 * 4] = bv;
    }
    __syncthreads();
#pragma unroll
    for (int k = 0; k < 32; ++k){
      float4 a = *(const float4*)&As[k][tm];
      float4 bv = *(const float4*)&Bs[k][tn];
      float av[4] = {a.x, a.y, a.z, a.w}, bb[4] = {bv.x, bv.y, bv.z, bv.w};
#pragma unroll
      for (int i = 0; i < 4; i++)
#pragma unroll
        for (int j = 0; j < 4; j++) acc[i][j] = fmaf(av[i], bb[j], acc[i][j]);
    }
    __syncthreads();
  }
#pragma unroll
  for (int i = 0; i < 4; i++)
#pragma unroll
    for (int j = 0; j < 4; j++)
      qi[(size_t)(m0 + tm + i) * 1024 + n0 + tn + j] = acc[i][j];
}

// ---------------- kernel 4: q_eff[s,d] = DI^-0.5 * sum_h wgt[s,h]*qi[s,h*64+d] ----------------
__global__ __launch_bounds__(256) void k_qeff(const float* __restrict__ qi,
                                              const float* __restrict__ wgt,
                                              float* __restrict__ qe){
  const int id = blockIdx.x * 256 + threadIdx.x;  // S*64 total
  const int s = id >> 6, d = id & 63;
  float acc = 0.f;
#pragma unroll
  for (int h = 0; h < 16; h++)
    acc = fmaf(wgt[(size_t)s * 16 + h], qi[(size_t)s * 1024 + h * 64 + d], acc);
  qe[(size_t)s * 64 + d] = acc * 0.125f;   // DI^-0.5
}

// ---------------- kernel 5: scores[i,j] = q_eff[i] . ki[j]  (lower-triangular tiles only) ----------------
__global__ __launch_bounds__(256) void k_scores(const float* __restrict__ qe,
                                                const float* __restrict__ ki,
                                                float* __restrict__ sc){
  const int bj = blockIdx.x, bi = blockIdx.y;
  if (bj > bi) return;
  const int t = threadIdx.x;
  const int i0 = bi * 64, j0 = bj * 64;
  __shared__ float Qs[64][68];  // [d][i]
  __shared__ float Ks[64][68];  // [d][j]
#pragma unroll
  for (int u0 = 0; u0 < 4; ++u0){
    int u = t + u0 * 256;
    int r = u >> 4, d4 = u & 15;
    float4 a = *(const float4*)&qe[(size_t)(i0 + r) * 64 + d4 * 4];
    Qs[d4*4+0][r] = a.x; Qs[d4*4+1][r] = a.y; Qs[d4*4+2][r] = a.z; Qs[d4*4+3][r] = a.w;
    float4 b = *(const float4*)&ki[(size_t)(j0 + r) * 64 + d4 * 4];
    Ks[d4*4+0][r] = b.x; Ks[d4*4+1][r] = b.y; Ks[d4*4+2][r] = b.z; Ks[d4*4+3][r] = b.w;
  }
  __syncthreads();
  const int tm = (t & 15) * 4, tn = (t >> 4) * 4;
  float acc[4][4] = {};
#pragma unroll
  for (int d = 0; d < 64; ++d){
    float4 a = *(const float4*)&Qs[d][tm];
    float4 b = *(const float4*)&Ks[d][tn];
    float av[4] = {a.x, a.y, a.z, a.w}, bb[4] = {b.x, b.y, b.z, b.w};
#pragma unroll
    for (int i = 0; i < 4; i++)
#pragma unroll
      for (int j = 0; j < 4; j++) acc[i][j] = fmaf(av[i], bb[j], acc[i][j]);
  }
#pragma unroll
  for (int i = 0; i < 4; i++)
#pragma unroll
    for (int j = 0; j < 4; j++)
      sc[(size_t)(i0 + tm + i) * S + j0 + tn + j] = acc[i][j];
}

// ---------------- kernel 6: per-row causal top-128 via 4-pass radix select ----------------
__global__ __launch_bounds__(256) void k_topk(const float* __restrict__ sc,
                                              int* __restrict__ idx,
                                              int* __restrict__ cnt){
  const int i = blockIdx.x, t = threadIdx.x;
  const int n = i + 1;           // valid causal candidates
  int* outr = idx + (size_t)i * TOPK;
  if (n <= TOPK){
    for (int m = t; m < n; m += 256) outr[m] = m;
    if (t == 0) cnt[i] = n;
    return;
  }
  __shared__ unsigned int keys[S];
  __shared__ int tl[S];
  __shared__ int hist[256];
  __shared__ int s_b, s_above, s_gt, s_eq;
  for (int j = t; j < n; j += 256){
    unsigned int u = __float_as_uint(sc[(size_t)i * S + j]);
    keys[j] = (u & 0x80000000u) ? ~u : (u | 0x80000000u);   // order-preserving key
  }
  unsigned int prefix = 0;
  int rem = TOPK;
  for (int p = 3; p >= 0; --p){
    const int sh = p * 8;
    __syncthreads();
    hist[t] = 0;
    __syncthreads();
    const unsigned int himask = (p == 3) ? 0u : (0xFFFFFFFFu << (sh + 8));
    for (int j = t; j < n; j += 256){
      unsigned int kk = keys[j];
      if ((kk & himask) == (prefix & himask)) atomicAdd(&hist[(kk >> sh) & 255], 1);
    }
    __syncthreads();
    if (t == 0){
      int cum = 0, b = 255;
      for (int d = 255; d >= 0; --d){
        if (cum + hist[d] >= rem){ b = d; break; }
        cum += hist[d];
      }
      s_b = b; s_above = cum;
    }
    __syncthreads();
    prefix |= ((unsigned int)s_b) << sh;
    rem -= s_above;
  }
  if (t == 0){ s_gt = 0; s_eq = 0; }
  __syncthreads();
  for (int j = t; j < n; j += 256){
    unsigned int kk = keys[j];
    if (kk > prefix){ int p = atomicAdd(&s_gt, 1); outr[p] = j; }
    else if (kk == prefix){ int p = atomicAdd(&s_eq, 1); tl[p] = j; }
  }
  __syncthreads();
  const int base = s_gt;          // == TOPK - rem
  if (s_eq == rem){
    for (int m = t; m < rem; m += 256) outr[base + m] = tl[m];
  } else if (t == 0){             // rare exact-tie path: lowest indices first
    int taken = 0;
    for (int j = 0; j < n && taken < rem; ++j)
      if (keys[j] == prefix) outr[base + taken++] = j;
  }
  if (t == 0) cnt[i] = TOPK;
}

// ---------------- kernel 7: gathered sparse attention (group-coalesced QK, coalesced PV) ----------------
__global__ __launch_bounds__(256) void k_attn(const float* __restrict__ q,
                                              const float* __restrict__ k,
                                              const float* __restrict__ v,
                                              const int* __restrict__ idx,
                                              const int* __restrict__ cnt,
                                              float* __restrict__ out){
  const int i = blockIdx.x;
  const int t = threadIdx.x;
  const int w = t >> 6, l = t & 63;
  const int n = cnt[i];
  const int* irow = idx + (size_t)i * TOPK;

  __shared__ int   sidx[TOPK];
  __shared__ float sq[NH][64];
  __shared__ float sp[NH][TOPK];

  if (t < TOPK) sidx[t] = (t < n) ? irow[t] : 0;
  for (int u = t; u < NH * 64; u += 256)
    sq[u >> 6][u & 63] = q[(size_t)i * (NH * 64) + u] * 0.125f;   // DQK^-0.5
  __syncthreads();

  const int h0 = w * 2, h1 = h0 + 1;
  const int g  = l >> 4;    // 16-lane group 0..3 (handles one key row per pass)
  const int gl = l & 15;    // lane within group -> 4 dims

  // ---- QK: per pass, each 16-lane group reads one key row slice coalesced (256B) ----
  const float4 qa = *(const float4*)&sq[h0][gl * 4];
  const float4 qb = *(const float4*)&sq[h1][gl * 4];
#pragma unroll 8
  for (int pass = 0; pass < TOPK / 4; ++pass){
    const int j = pass * 4 + g;
    const float* kb = k + (size_t)sidx[j] * (NH * 64);
    float4 k0 = *(const float4*)&kb[h0 * 64 + gl * 4];
    float4 k1 = *(const float4*)&kb[h1 * 64 + gl * 4];
    float d0 = fmaf(qa.x, k0.x, fmaf(qa.y, k0.y, fmaf(qa.z, k0.z, qa.w * k0.w)));
    float d1 = fmaf(qb.x, k1.x, fmaf(qb.y, k1.y, fmaf(qb.z, k1.z, qb.w * k1.w)));
#pragma unroll
    for (int o = 1; o < 16; o <<= 1){
      d0 += __shfl_xor(d0, o);
      d1 += __shfl_xor(d1, o);
    }
    if (gl == 0){ sp[h0][j] = d0; sp[h1][j] = d1; }
  }

  // ---- softmax per head across the wave (2 entries per lane) ----
  const bool v0 = (l < n), v1 = (l + 64 < n);
  {
    float s0 = v0 ? sp[h0][l] : -1e30f, s1 = v1 ? sp[h0][l + 64] : -1e30f;
    float m = wave_max(fmaxf(s0, s1));
    float e0 = v0 ? __expf(s0 - m) : 0.f;
    float e1 = v1 ? __expf(s1 - m) : 0.f;
    float inv = 1.f / wave_sum(e0 + e1);
    sp[h0][l] = e0 * inv;
    sp[h0][l + 64] = e1 * inv;
  }
  {
    float s0 = v0 ? sp[h1][l] : -1e30f, s1 = v1 ? sp[h1][l + 64] : -1e30f;
    float m = wave_max(fmaxf(s0, s1));
    float e0 = v0 ? __expf(s0 - m) : 0.f;
    float e1 = v1 ? __expf(s1 - m) : 0.f;
    float inv = 1.f / wave_sum(e0 + e1);
    sp[h1][l] = e0 * inv;
    sp[h1][l + 64] = e1 * inv;
  }
  __syncthreads();

  // ---- PV: lane l = output dim; coalesced 256B reads per key row ----
  float o0 = 0.f, o1 = 0.f;
#pragma unroll 4
  for (int j = 0; j < n; ++j){
    const float* vb = v + (size_t)sidx[j] * (NH * 64);
    o0 = fmaf(sp[h0][j], vb[h0 * 64 + l], o0);
    o1 = fmaf(sp[h1][j], vb[h1 * 64 + l], o1);
  }
  out[((size_t)i * NH + h0) * 64 + l] = o0;
  out[((size_t)i * NH + h1) * 64 + l] = o1;
}

extern "C" void kernel_launch(void* const* d_in, const int* in_sizes, int n_in,
                              void* d_out, int out_size, void* d_ws, size_t ws_size,
                              hipStream_t stream){
  const float* x   = (const float*)d_in[0];
  const float* qin = (const float*)d_in[1];
  const float* q   = (const float*)d_in[2];
  const float* k   = (const float*)d_in[3];
  const float* v   = (const float*)d_in[4];
  const float* wq  = (const float*)d_in[5];
  const float* wk  = (const float*)d_in[6];
  const float* lng = (const float*)d_in[7];
  const float* lnb = (const float*)d_in[8];
  const float* ww  = (const float*)d_in[9];
  float* out = (float*)d_out;

  float* ws   = (float*)d_ws;
  float* part = ws;                  // 4*2048*80   = 655360
  float* ki   = ws + 655360;         // 2048*64     = 131072
  float* wgt  = ws + 786432;         // 2048*16     = 32768
  float* qi   = ws + 819200;         // 2048*1024   = 2097152
  float* qe   = ws + 2916352;        // 2048*64     = 131072
  float* sc   = ws + 3047424;        // 2048*2048   = 4194304
  int*   idx  = (int*)(ws + 7241728);// 2048*128 ints
  int*   cnt  = (int*)(ws + 7503872);// 2048 ints

  hipLaunchKernelGGL(k_part,   dim3(4, 32),  dim3(256), 0, stream, x, wk, ww, part);
  hipLaunchKernelGGL(k_lnw,    dim3(2048),   dim3(64),  0, stream, part, lng, lnb, ki, wgt);
  hipLaunchKernelGGL(k_qi,     dim3(16, 32), dim3(256), 0, stream, qin, wq, qi);
  hipLaunchKernelGGL(k_qeff,   dim3(512),    dim3(256), 0, stream, qi, wgt, qe);
  hipLaunchKernelGGL(k_scores, dim3(32, 32), dim3(256), 0, stream, qe, ki, sc);
  hipLaunchKernelGGL(k_topk,   dim3(2048),   dim3(256), 0, stream, sc, idx, cnt);
  hipLaunchKernelGGL(k_attn,   dim3(2048),   dim3(256), 0, stream, q, k, v, idx, cnt, out);
}

// Round 4
// 137.424 us; speedup vs baseline: 2.3825x; 1.2585x over previous
//
#include <hip/hip_runtime.h>
#include <hip/hip_bf16.h>
#include <math.h>

#define S 2048
#define DM 1024
#define QIN 512
#define HI 16
#define DI 64
#define NH 8
#define TOPK 128
#define LN_EPS 1e-5f

__device__ __forceinline__ float wave_sum(float v){
#pragma unroll
  for (int o = 32; o; o >>= 1) v += __shfl_xor(v, o);
  return v;
}
__device__ __forceinline__ float wave_max(float v){
#pragma unroll
  for (int o = 32; o; o >>= 1) v = fmaxf(v, __shfl_xor(v, o));
  return v;
}
__device__ __forceinline__ unsigned short f2bf(float x){
  unsigned u = __float_as_uint(x);
  unsigned r = u + 0x7FFFu + ((u >> 16) & 1u);   // RN-even
  return (unsigned short)(r >> 16);
}
__device__ __forceinline__ float bf2f(unsigned short s){
  return __uint_as_float(((unsigned)s) << 16);
}

// ---------------- kernel 0: f32 -> bf16 conversion (K,V for attention gather) ----------------
__global__ __launch_bounds__(256) void k_cvt(const float* __restrict__ src,
                                             unsigned short* __restrict__ dst, int n4){
  int id = blockIdx.x * 256 + threadIdx.x;
  if (id >= n4) return;
  float4 f = ((const float4*)src)[id];
  ushort4 o;
  o.x = f2bf(f.x); o.y = f2bf(f.y); o.z = f2bf(f.z); o.w = f2bf(f.w);
  ((ushort4*)dst)[id] = o;
}

// ---------------- kernel 1: split-K partial GEMM  x(2048x1024) @ [w_k | w_weights](1024x80) ----------------
__global__ __launch_bounds__(256) void k_part(const float* __restrict__ x,
                                              const float* __restrict__ wk,
                                              const float* __restrict__ ww,
                                              float* __restrict__ part){
  const int kp = blockIdx.x;   // 0..3 (K split)
  const int bm = blockIdx.y;   // 0..31
  const int t  = threadIdx.x;
  const int m0 = bm * 64;
  __shared__ float As[32][68];  // [k][m]
  __shared__ float Bs[32][84];  // [k][n]
  const int tm = (t & 15) * 4;
  const int tn = (t >> 4) * 5;
  float acc[4][5];
#pragma unroll
  for (int i = 0; i < 4; i++)
#pragma unroll
    for (int j = 0; j < 5; j++) acc[i][j] = 0.f;

  for (int kb = 0; kb < 8; ++kb){
    const int k0 = kp * 256 + kb * 32;
#pragma unroll
    for (int i = 0; i < 2; i++){
      int u = t + i * 256;
      int m = u >> 3, c4 = u & 7;
      float4 a = *(const float4*)&x[(size_t)(m0 + m) * DM + k0 + c4 * 4];
      As[c4*4+0][m] = a.x; As[c4*4+1][m] = a.y; As[c4*4+2][m] = a.z; As[c4*4+3][m] = a.w;
    }
#pragma unroll
    for (int i = 0; i < 10; i++){
      int u = t + i * 256;
      int kk = u / 80, nn = u % 80;
      float val = (nn < 64) ? wk[(size_t)(k0 + kk) * 64 + nn]
                            : ww[(size_t)(k0 + kk) * 16 + (nn - 64)];
      Bs[kk][nn] = val;
    }
    __syncthreads();
#pragma unroll
    for (int k = 0; k < 32; ++k){
      float4 a = *(const float4*)&As[k][tm];
      float av[4] = {a.x, a.y, a.z, a.w};
      float bb[5];
#pragma unroll
      for (int j = 0; j < 5; j++) bb[j] = Bs[k][tn + j];
#pragma unroll
      for (int i = 0; i < 4; i++)
#pragma unroll
        for (int j = 0; j < 5; j++) acc[i][j] = fmaf(av[i], bb[j], acc[i][j]);
    }
    __syncthreads();
  }
  float* dst = part + (size_t)kp * S * 80;
#pragma unroll
  for (int i = 0; i < 4; i++)
#pragma unroll
    for (int j = 0; j < 5; j++)
      dst[(size_t)(m0 + tm + i) * 80 + tn + j] = acc[i][j];
}

// ---------------- kernel 2: reduce split-K partials, LayerNorm(ki), scale wgt ----------------
__global__ __launch_bounds__(64) void k_lnw(const float* __restrict__ part,
                                            const float* __restrict__ g,
                                            const float* __restrict__ b,
                                            float* __restrict__ ki,
                                            float* __restrict__ wgt){
  const int s = blockIdx.x, l = threadIdx.x;
  float kv = 0.f;
#pragma unroll
  for (int p = 0; p < 4; p++) kv += part[(size_t)p * S * 80 + (size_t)s * 80 + l];
  float wv = 0.f;
  if (l < 16){
#pragma unroll
    for (int p = 0; p < 4; p++) wv += part[(size_t)p * S * 80 + (size_t)s * 80 + 64 + l];
  }
  float mu = wave_sum(kv) * (1.f / 64.f);
  float d  = kv - mu;
  float var = wave_sum(d * d) * (1.f / 64.f);
  float o = d * (1.f / sqrtf(var + LN_EPS)) * g[l] + b[l];
  ki[(size_t)s * 64 + l] = o;
  if (l < 16) wgt[(size_t)s * 16 + l] = wv * 0.25f;   // HI^-0.5
}

// ---------------- kernel 3: qi = q_input(2048x512) @ w_q(512x1024), 64x128 tile ----------------
__global__ __launch_bounds__(256) void k_qi(const float* __restrict__ qin,
                                            const float* __restrict__ wq,
                                            float* __restrict__ qi){
  const int bn = blockIdx.x;   // 0..7  (128-wide N)
  const int bm = blockIdx.y;   // 0..31 (64-tall M)
  const int t = threadIdx.x;
  const int m0 = bm * 64, n0 = bn * 128;
  __shared__ float As[32][68];
  __shared__ float Bs[32][132];
  const int tm = (t & 15) * 4;
  const int tn = (t >> 4) * 8;
  float acc[4][8] = {};
  for (int kb = 0; kb < 16; ++kb){
    const int k0 = kb * 32;
#pragma unroll
    for (int i2 = 0; i2 < 2; i2++){
      int u = t + i2 * 256;
      int m = u >> 3, c4 = u & 7;
      float4 a = *(const float4*)&qin[(size_t)(m0 + m) * QIN + k0 + c4 * 4];
      As[c4*4+0][m] = a.x; As[c4*4+1][m] = a.y; As[c4*4+2][m] = a.z; As[c4*4+3][m] = a.w;
    }
#pragma unroll
    for (int i2 = 0; i2 < 4; i2++){
      int u = t + i2 * 256;
      int kk = u >> 5, n4 = u & 31;
      *(float4*)&Bs[kk][n4 * 4] = *(const float4*)&wq[(size_t)(k0 + kk) * 1024 + n0 + n4 * 4];
    }
    __syncthreads();
#pragma unroll
    for (int kk = 0; kk < 32; ++kk){
      float4 a  = *(const float4*)&As[kk][tm];
      float4 b0 = *(const float4*)&Bs[kk][tn];
      float4 b1 = *(const float4*)&Bs[kk][tn + 4];
      float av[4] = {a.x, a.y, a.z, a.w};
      float bv[8] = {b0.x, b0.y, b0.z, b0.w, b1.x, b1.y, b1.z, b1.w};
#pragma unroll
      for (int i = 0; i < 4; i++)
#pragma unroll
        for (int j = 0; j < 8; j++) acc[i][j] = fmaf(av[i], bv[j], acc[i][j]);
    }
    __syncthreads();
  }
#pragma unroll
  for (int i = 0; i < 4; i++){
    *(float4*)&qi[(size_t)(m0 + tm + i) * 1024 + n0 + tn]     = make_float4(acc[i][0], acc[i][1], acc[i][2], acc[i][3]);
    *(float4*)&qi[(size_t)(m0 + tm + i) * 1024 + n0 + tn + 4] = make_float4(acc[i][4], acc[i][5], acc[i][6], acc[i][7]);
  }
}

// ---------------- kernel 4: q_eff[s,d] = DI^-0.5 * sum_h wgt[s,h]*qi[s,h*64+d] ----------------
__global__ __launch_bounds__(256) void k_qeff(const float* __restrict__ qi,
                                              const float* __restrict__ wgt,
                                              float* __restrict__ qe){
  const int id = blockIdx.x * 256 + threadIdx.x;  // S*64 total
  const int s = id >> 6, d = id & 63;
  float acc = 0.f;
#pragma unroll
  for (int h = 0; h < 16; h++)
    acc = fmaf(wgt[(size_t)s * 16 + h], qi[(size_t)s * 1024 + h * 64 + d], acc);
  qe[(size_t)s * 64 + d] = acc * 0.125f;   // DI^-0.5
}

// ---------------- kernel 5: scores[i,j] = q_eff[i] . ki[j]  (lower-triangular tiles only) ----------------
__global__ __launch_bounds__(256) void k_scores(const float* __restrict__ qe,
                                                const float* __restrict__ ki,
                                                float* __restrict__ sc){
  const int bj = blockIdx.x, bi = blockIdx.y;
  if (bj > bi) return;
  const int t = threadIdx.x;
  const int i0 = bi * 64, j0 = bj * 64;
  __shared__ float Qs[64][68];  // [d][i]
  __shared__ float Ks[64][68];  // [d][j]
#pragma unroll
  for (int u0 = 0; u0 < 4; ++u0){
    int u = t + u0 * 256;
    int r = u >> 4, d4 = u & 15;
    float4 a = *(const float4*)&qe[(size_t)(i0 + r) * 64 + d4 * 4];
    Qs[d4*4+0][r] = a.x; Qs[d4*4+1][r] = a.y; Qs[d4*4+2][r] = a.z; Qs[d4*4+3][r] = a.w;
    float4 b = *(const float4*)&ki[(size_t)(j0 + r) * 64 + d4 * 4];
    Ks[d4*4+0][r] = b.x; Ks[d4*4+1][r] = b.y; Ks[d4*4+2][r] = b.z; Ks[d4*4+3][r] = b.w;
  }
  __syncthreads();
  const int tm = (t & 15) * 4, tn = (t >> 4) * 4;
  float acc[4][4] = {};
#pragma unroll
  for (int d = 0; d < 64; ++d){
    float4 a = *(const float4*)&Qs[d][tm];
    float4 b = *(const float4*)&Ks[d][tn];
    float av[4] = {a.x, a.y, a.z, a.w}, bb[4] = {b.x, b.y, b.z, b.w};
#pragma unroll
    for (int i = 0; i < 4; i++)
#pragma unroll
      for (int j = 0; j < 4; j++) acc[i][j] = fmaf(av[i], bb[j], acc[i][j]);
  }
#pragma unroll
  for (int i = 0; i < 4; i++)
#pragma unroll
    for (int j = 0; j < 4; j++)
      sc[(size_t)(i0 + tm + i) * S + j0 + tn + j] = acc[i][j];
}

// ---------------- kernel 6: per-row causal top-128 via 4-pass radix select ----------------
__global__ __launch_bounds__(256) void k_topk(const float* __restrict__ sc,
                                              int* __restrict__ idx,
                                              int* __restrict__ cnt){
  const int i = blockIdx.x, t = threadIdx.x;
  const int n = i + 1;           // valid causal candidates
  int* outr = idx + (size_t)i * TOPK;
  if (n <= TOPK){
    for (int m = t; m < n; m += 256) outr[m] = m;
    if (t == 0) cnt[i] = n;
    return;
  }
  __shared__ unsigned int keys[S];
  __shared__ int tl[S];
  __shared__ int hist[256];
  __shared__ int ssum[256];
  __shared__ int s_b, s_above, s_gt, s_eq;
  for (int j = t; j < n; j += 256){
    unsigned int u = __float_as_uint(sc[(size_t)i * S + j]);
    keys[j] = (u & 0x80000000u) ? ~u : (u | 0x80000000u);   // order-preserving key
  }
  unsigned int prefix = 0;
  int rem = TOPK;
  for (int p = 3; p >= 0; --p){
    const int sh = p * 8;
    __syncthreads();
    hist[t] = 0;
    __syncthreads();
    const unsigned int himask = (p == 3) ? 0u : (0xFFFFFFFFu << (sh + 8));
    for (int j = t; j < n; j += 256){
      unsigned int kk = keys[j];
      if ((kk & himask) == (prefix & himask)) atomicAdd(&hist[(kk >> sh) & 255], 1);
    }
    __syncthreads();
    // parallel suffix-sum over 256 bins (Hillis-Steele)
    ssum[t] = hist[t];
    __syncthreads();
#pragma unroll
    for (int off = 1; off < 256; off <<= 1){
      int add = (t + off < 256) ? ssum[t + off] : 0;
      __syncthreads();
      ssum[t] += add;
      __syncthreads();
    }
    int excl = ssum[t] - hist[t];          // count of keys in bins > t
    if (excl < rem && excl + hist[t] >= rem){ s_b = t; s_above = excl; }
    __syncthreads();
    prefix |= ((unsigned int)s_b) << sh;
    rem -= s_above;
  }
  if (t == 0){ s_gt = 0; s_eq = 0; }
  __syncthreads();
  for (int j = t; j < n; j += 256){
    unsigned int kk = keys[j];
    if (kk > prefix){ int p = atomicAdd(&s_gt, 1); outr[p] = j; }
    else if (kk == prefix){ int p = atomicAdd(&s_eq, 1); tl[p] = j; }
  }
  __syncthreads();
  const int base = s_gt;          // == TOPK - rem
  if (s_eq == rem){
    for (int m = t; m < rem; m += 256) outr[base + m] = tl[m];
  } else if (t == 0){             // rare exact-tie path: lowest indices first
    int taken = 0;
    for (int j = 0; j < n && taken < rem; ++j)
      if (keys[j] == prefix) outr[base + taken++] = j;
  }
  if (t == 0) cnt[i] = TOPK;
}

// ---------------- kernel 7: gathered sparse attention (bf16 K/V, coalesced) ----------------
__global__ __launch_bounds__(256) void k_attn(const float* __restrict__ q,
                                              const unsigned short* __restrict__ kh,
                                              const unsigned short* __restrict__ vh,
                                              const int* __restrict__ idx,
                                              const int* __restrict__ cnt,
                                              float* __restrict__ out){
  const int i = blockIdx.x;
  const int t = threadIdx.x;
  const int w = t >> 6, l = t & 63;
  const int n = cnt[i];
  const int* irow = idx + (size_t)i * TOPK;

  __shared__ int   sidx[TOPK];
  __shared__ float sq[NH][64];
  __shared__ float sp[NH][TOPK];

  if (t < TOPK) sidx[t] = (t < n) ? irow[t] : 0;
  for (int u = t; u < NH * 64; u += 256)
    sq[u >> 6][u & 63] = q[(size_t)i * (NH * 64) + u] * 0.125f;   // DQK^-0.5
  __syncthreads();

  const int h0 = w * 2, h1 = h0 + 1;

  // ---- QK: 8-lane groups; group g handles key j=pass*8+g; lane covers 8 dims (16B bf16) ----
  const int g  = l >> 3;
  const int gl = l & 7;
  float qa[8], qb[8];
#pragma unroll
  for (int e = 0; e < 8; ++e){ qa[e] = sq[h0][gl * 8 + e]; qb[e] = sq[h1][gl * 8 + e]; }
#pragma unroll 4
  for (int pass = 0; pass < TOPK / 8; ++pass){
    const int j = pass * 8 + g;
    const size_t base = (size_t)sidx[j] * (NH * 64);
    uint4 u0 = *(const uint4*)(kh + base + h0 * 64 + gl * 8);
    uint4 u1 = *(const uint4*)(kh + base + h1 * 64 + gl * 8);
    float d0 = 0.f, d1 = 0.f;
    d0 = fmaf(__uint_as_float(u0.x << 16),         qa[0], d0);
    d0 = fmaf(__uint_as_float(u0.x & 0xFFFF0000u), qa[1], d0);
    d0 = fmaf(__uint_as_float(u0.y << 16),         qa[2], d0);
    d0 = fmaf(__uint_as_float(u0.y & 0xFFFF0000u), qa[3], d0);
    d0 = fmaf(__uint_as_float(u0.z << 16),         qa[4], d0);
    d0 = fmaf(__uint_as_float(u0.z & 0xFFFF0000u), qa[5], d0);
    d0 = fmaf(__uint_as_float(u0.w << 16),         qa[6], d0);
    d0 = fmaf(__uint_as_float(u0.w & 0xFFFF0000u), qa[7], d0);
    d1 = fmaf(__uint_as_float(u1.x << 16),         qb[0], d1);
    d1 = fmaf(__uint_as_float(u1.x & 0xFFFF0000u), qb[1], d1);
    d1 = fmaf(__uint_as_float(u1.y << 16),         qb[2], d1);
    d1 = fmaf(__uint_as_float(u1.y & 0xFFFF0000u), qb[3], d1);
    d1 = fmaf(__uint_as_float(u1.z << 16),         qb[4], d1);
    d1 = fmaf(__uint_as_float(u1.z & 0xFFFF0000u), qb[5], d1);
    d1 = fmaf(__uint_as_float(u1.w << 16),         qb[6], d1);
    d1 = fmaf(__uint_as_float(u1.w & 0xFFFF0000u), qb[7], d1);
#pragma unroll
    for (int o = 1; o < 8; o <<= 1){ d0 += __shfl_xor(d0, o); d1 += __shfl_xor(d1, o); }
    if (gl == 0){ sp[h0][j] = d0; sp[h1][j] = d1; }
  }

  // ---- softmax per head across the wave (2 entries per lane) ----
  const bool v0 = (l < n), v1 = (l + 64 < n);
  {
    float s0 = v0 ? sp[h0][l] : -1e30f, s1 = v1 ? sp[h0][l + 64] : -1e30f;
    float m = wave_max(fmaxf(s0, s1));
    float e0 = v0 ? __expf(s0 - m) : 0.f;
    float e1 = v1 ? __expf(s1 - m) : 0.f;
    float inv = 1.f / wave_sum(e0 + e1);
    sp[h0][l] = e0 * inv;
    sp[h0][l + 64] = e1 * inv;
  }
  {
    float s0 = v0 ? sp[h1][l] : -1e30f, s1 = v1 ? sp[h1][l + 64] : -1e30f;
    float m = wave_max(fmaxf(s0, s1));
    float e0 = v0 ? __expf(s0 - m) : 0.f;
    float e1 = v1 ? __expf(s1 - m) : 0.f;
    float inv = 1.f / wave_sum(e0 + e1);
    sp[h1][l] = e0 * inv;
    sp[h1][l + 64] = e1 * inv;
  }

  // ---- PV: one wave-load covers 2 keys x 2 heads (8B bf16 per lane) ----
  const int j2 = l >> 5;               // key parity
  const int hh = w * 2 + ((l >> 4) & 1);
  const int g4 = l & 15;               // 4 dims
  float o4[4] = {0.f, 0.f, 0.f, 0.f};
#pragma unroll 4
  for (int pass = 0; pass < TOPK / 2; ++pass){
    const int j = pass * 2 + j2;
    const size_t base = (size_t)sidx[j] * (NH * 64);
    ushort4 uv = *(const ushort4*)(vh + base + hh * 64 + g4 * 4);
    float p = sp[hh][j];
    o4[0] = fmaf(p, bf2f(uv.x), o4[0]);
    o4[1] = fmaf(p, bf2f(uv.y), o4[1]);
    o4[2] = fmaf(p, bf2f(uv.z), o4[2]);
    o4[3] = fmaf(p, bf2f(uv.w), o4[3]);
  }
#pragma unroll
  for (int e = 0; e < 4; ++e) o4[e] += __shfl_xor(o4[e], 32);
  if (l < 32)
    *(float4*)&out[((size_t)i * NH + hh) * 64 + g4 * 4] = make_float4(o4[0], o4[1], o4[2], o4[3]);
}

extern "C" void kernel_launch(void* const* d_in, const int* in_sizes, int n_in,
                              void* d_out, int out_size, void* d_ws, size_t ws_size,
                              hipStream_t stream){
  const float* x   = (const float*)d_in[0];
  const float* qin = (const float*)d_in[1];
  const float* q   = (const float*)d_in[2];
  const float* k   = (const float*)d_in[3];
  const float* v   = (const float*)d_in[4];
  const float* wq  = (const float*)d_in[5];
  const float* wk  = (const float*)d_in[6];
  const float* lng = (const float*)d_in[7];
  const float* lnb = (const float*)d_in[8];
  const float* ww  = (const float*)d_in[9];
  float* out = (float*)d_out;

  float* ws   = (float*)d_ws;
  float* part = ws;                  // 4*2048*80   = 655360
  float* ki   = ws + 655360;         // 2048*64     = 131072
  float* wgt  = ws + 786432;         // 2048*16     = 32768
  float* qi   = ws + 819200;         // 2048*1024   = 2097152
  float* qe   = ws + 2916352;        // 2048*64     = 131072
  float* sc   = ws + 3047424;        // 2048*2048   = 4194304
  int*   idx  = (int*)(ws + 7241728);// 2048*128 ints
  int*   cnt  = (int*)(ws + 7503872);// 2048 ints
  // bf16 K/V reuse the qi region (free after k_qeff): 2*1M ushorts = 4 MB < 8 MB
  unsigned short* kh = (unsigned short*)(ws + 819200);
  unsigned short* vh = kh + (size_t)S * NH * 64;

  hipLaunchKernelGGL(k_part,   dim3(4, 32),  dim3(256), 0, stream, x, wk, ww, part);
  hipLaunchKernelGGL(k_lnw,    dim3(2048),   dim3(64),  0, stream, part, lng, lnb, ki, wgt);
  hipLaunchKernelGGL(k_qi,     dim3(8, 32),  dim3(256), 0, stream, qin, wq, qi);
  hipLaunchKernelGGL(k_qeff,   dim3(512),    dim3(256), 0, stream, qi, wgt, qe);
  hipLaunchKernelGGL(k_cvt,    dim3(1024),   dim3(256), 0, stream, k, kh, S * NH * 64 / 4);
  hipLaunchKernelGGL(k_cvt,    dim3(1024),   dim3(256), 0, stream, v, vh, S * NH * 64 / 4);
  hipLaunchKernelGGL(k_scores, dim3(32, 32), dim3(256), 0, stream, qe, ki, sc);
  hipLaunchKernelGGL(k_topk,   dim3(2048),   dim3(256), 0, stream, sc, idx, cnt);
  hipLaunchKernelGGL(k_attn,   dim3(2048),   dim3(256), 0, stream, q, kh, vh, idx, cnt, out);
}

// Round 5
// 131.437 us; speedup vs baseline: 2.4910x; 1.0455x over previous
//
#include <hip/hip_runtime.h>
#include <hip/hip_bf16.h>
#include <math.h>

#define S 2048
#define DM 1024
#define QIN 512
#define HI 16
#define DI 64
#define NH 8
#define TOPK 128
#define LN_EPS 1e-5f

typedef float f32x4 __attribute__((ext_vector_type(4)));
typedef short s16x8 __attribute__((ext_vector_type(8)));

__device__ __forceinline__ float wave_sum(float v){
#pragma unroll
  for (int o = 32; o; o >>= 1) v += __shfl_xor(v, o);
  return v;
}
__device__ __forceinline__ float wave_max(float v){
#pragma unroll
  for (int o = 32; o; o >>= 1) v = fmaxf(v, __shfl_xor(v, o));
  return v;
}
__device__ __forceinline__ unsigned short f2bf(float x){
  unsigned u = __float_as_uint(x);
  unsigned r = u + 0x7FFFu + ((u >> 16) & 1u);   // RN-even
  return (unsigned short)(r >> 16);
}
__device__ __forceinline__ float bf2f(unsigned short s){
  return __uint_as_float(((unsigned)s) << 16);
}

// ---------------- kernel 0: f32 -> bf16 conversion (K,V for attention gather) ----------------
__global__ __launch_bounds__(256) void k_cvt(const float* __restrict__ src,
                                             unsigned short* __restrict__ dst, int n4){
  int id = blockIdx.x * 256 + threadIdx.x;
  if (id >= n4) return;
  float4 f = ((const float4*)src)[id];
  ushort4 o;
  o.x = f2bf(f.x); o.y = f2bf(f.y); o.z = f2bf(f.z); o.w = f2bf(f.w);
  ((ushort4*)dst)[id] = o;
}

// ---------------- kernel 0b: f32 -> split bf16 hi/lo (elementwise, for q_input) ----------------
__global__ __launch_bounds__(256) void k_splitA(const float* __restrict__ src,
                                                unsigned short* __restrict__ dh,
                                                unsigned short* __restrict__ dl, int n4){
  int id = blockIdx.x * 256 + threadIdx.x;
  if (id >= n4) return;
  float4 f = ((const float4*)src)[id];
  ushort4 h, l;
  h.x = f2bf(f.x); l.x = f2bf(f.x - bf2f(h.x));
  h.y = f2bf(f.y); l.y = f2bf(f.y - bf2f(h.y));
  h.z = f2bf(f.z); l.z = f2bf(f.z - bf2f(h.z));
  h.w = f2bf(f.w); l.w = f2bf(f.w - bf2f(h.w));
  ((ushort4*)dh)[id] = h;
  ((ushort4*)dl)[id] = l;
}

// ---------------- kernel 0c: w_q (512x1024) -> transposed split bf16 [n][k] hi/lo ----------------
__global__ __launch_bounds__(256) void k_trsplit(const float* __restrict__ wq,
                                                 unsigned short* __restrict__ bh,
                                                 unsigned short* __restrict__ bl){
  const int k0 = blockIdx.x * 32;   // 16 k-tiles
  const int n0 = blockIdx.y * 32;   // 32 n-tiles
  const int t = threadIdx.x;
  __shared__ unsigned short lh[32][33];
  __shared__ unsigned short ll[32][33];
  const int c = t & 31, r8 = t >> 5;
#pragma unroll
  for (int i = 0; i < 4; ++i){
    int kk = r8 + i * 8;
    float wv = wq[(size_t)(k0 + kk) * 1024 + n0 + c];
    unsigned short h = f2bf(wv);
    lh[c][kk] = h;
    ll[c][kk] = f2bf(wv - bf2f(h));
  }
  __syncthreads();
  const int kk = t & 31, nl = t >> 5;
#pragma unroll
  for (int i = 0; i < 4; ++i){
    int nn = nl + i * 8;
    bh[(size_t)(n0 + nn) * QIN + k0 + kk] = lh[nn][kk];
    bl[(size_t)(n0 + nn) * QIN + k0 + kk] = ll[nn][kk];
  }
}

// ---------------- kernel 1: split-K partial GEMM  x(2048x1024) @ [w_k | w_weights](1024x80) ----------------
__global__ __launch_bounds__(256) void k_part(const float* __restrict__ x,
                                              const float* __restrict__ wk,
                                              const float* __restrict__ ww,
                                              float* __restrict__ part){
  const int kp = blockIdx.x;   // 0..3 (K split)
  const int bm = blockIdx.y;   // 0..31
  const int t  = threadIdx.x;
  const int m0 = bm * 64;
  __shared__ float As[32][68];  // [k][m]
  __shared__ float Bs[32][84];  // [k][n]
  const int tm = (t & 15) * 4;
  const int tn = (t >> 4) * 5;
  float acc[4][5];
#pragma unroll
  for (int i = 0; i < 4; i++)
#pragma unroll
    for (int j = 0; j < 5; j++) acc[i][j] = 0.f;

  for (int kb = 0; kb < 8; ++kb){
    const int k0 = kp * 256 + kb * 32;
#pragma unroll
    for (int i = 0; i < 2; i++){
      int u = t + i * 256;
      int m = u >> 3, c4 = u & 7;
      float4 a = *(const float4*)&x[(size_t)(m0 + m) * DM + k0 + c4 * 4];
      As[c4*4+0][m] = a.x; As[c4*4+1][m] = a.y; As[c4*4+2][m] = a.z; As[c4*4+3][m] = a.w;
    }
#pragma unroll
    for (int i = 0; i < 10; i++){
      int u = t + i * 256;
      int kk = u / 80, nn = u % 80;
      float val = (nn < 64) ? wk[(size_t)(k0 + kk) * 64 + nn]
                            : ww[(size_t)(k0 + kk) * 16 + (nn - 64)];
      Bs[kk][nn] = val;
    }
    __syncthreads();
#pragma unroll
    for (int k = 0; k < 32; ++k){
      float4 a = *(const float4*)&As[k][tm];
      float av[4] = {a.x, a.y, a.z, a.w};
      float bb[5];
#pragma unroll
      for (int j = 0; j < 5; j++) bb[j] = Bs[k][tn + j];
#pragma unroll
      for (int i = 0; i < 4; i++)
#pragma unroll
        for (int j = 0; j < 5; j++) acc[i][j] = fmaf(av[i], bb[j], acc[i][j]);
    }
    __syncthreads();
  }
  float* dst = part + (size_t)kp * S * 80;
#pragma unroll
  for (int i = 0; i < 4; i++)
#pragma unroll
    for (int j = 0; j < 5; j++)
      dst[(size_t)(m0 + tm + i) * 80 + tn + j] = acc[i][j];
}

// ---------------- kernel 2: reduce split-K partials, LayerNorm(ki), scale wgt ----------------
__global__ __launch_bounds__(64) void k_lnw(const float* __restrict__ part,
                                            const float* __restrict__ g,
                                            const float* __restrict__ b,
                                            float* __restrict__ ki,
                                            float* __restrict__ wgt){
  const int s = blockIdx.x, l = threadIdx.x;
  float kv = 0.f;
#pragma unroll
  for (int p = 0; p < 4; p++) kv += part[(size_t)p * S * 80 + (size_t)s * 80 + l];
  float wv = 0.f;
  if (l < 16){
#pragma unroll
    for (int p = 0; p < 4; p++) wv += part[(size_t)p * S * 80 + (size_t)s * 80 + 64 + l];
  }
  float mu = wave_sum(kv) * (1.f / 64.f);
  float d  = kv - mu;
  float var = wave_sum(d * d) * (1.f / 64.f);
  float o = d * (1.f / sqrtf(var + LN_EPS)) * g[l] + b[l];
  ki[(size_t)s * 64 + l] = o;
  if (l < 16) wgt[(size_t)s * 16 + l] = wv * 0.25f;   // HI^-0.5
}

// ---------------- kernel 3: qi = q_input @ w_q via split-bf16 MFMA (AhBh + AhBl + AlBh) ----------------
__global__ __launch_bounds__(256) void k_qi_mfma(const unsigned short* __restrict__ Ah,
                                                 const unsigned short* __restrict__ Al,
                                                 const unsigned short* __restrict__ Bh,
                                                 const unsigned short* __restrict__ Bl,
                                                 float* __restrict__ qi){
  const int bn = blockIdx.x;   // 0..15
  const int bm = blockIdx.y;   // 0..31
  const int w = threadIdx.x >> 6, l = threadIdx.x & 63;
  const int m0 = bm * 64 + (w >> 1) * 32;
  const int n0 = bn * 64 + (w & 1) * 32;
  const int r = l & 15, kg = l >> 4;

  f32x4 acc00 = {0,0,0,0}, acc01 = {0,0,0,0}, acc10 = {0,0,0,0}, acc11 = {0,0,0,0};

  const size_t aoff = (size_t)(m0 + r) * QIN + kg * 8;
  const size_t boff = (size_t)(n0 + r) * QIN + kg * 8;
#pragma unroll 4
  for (int k0 = 0; k0 < QIN; k0 += 32){
    s16x8 ah0 = *(const s16x8*)(Ah + aoff + k0);
    s16x8 ah1 = *(const s16x8*)(Ah + aoff + 16 * QIN + k0);
    s16x8 al0 = *(const s16x8*)(Al + aoff + k0);
    s16x8 al1 = *(const s16x8*)(Al + aoff + 16 * QIN + k0);
    s16x8 bh0 = *(const s16x8*)(Bh + boff + k0);
    s16x8 bh1 = *(const s16x8*)(Bh + boff + 16 * QIN + k0);
    s16x8 bl0 = *(const s16x8*)(Bl + boff + k0);
    s16x8 bl1 = *(const s16x8*)(Bl + boff + 16 * QIN + k0);
    acc00 = __builtin_amdgcn_mfma_f32_16x16x32_bf16(ah0, bh0, acc00, 0, 0, 0);
    acc00 = __builtin_amdgcn_mfma_f32_16x16x32_bf16(ah0, bl0, acc00, 0, 0, 0);
    acc00 = __builtin_amdgcn_mfma_f32_16x16x32_bf16(al0, bh0, acc00, 0, 0, 0);
    acc01 = __builtin_amdgcn_mfma_f32_16x16x32_bf16(ah0, bh1, acc01, 0, 0, 0);
    acc01 = __builtin_amdgcn_mfma_f32_16x16x32_bf16(ah0, bl1, acc01, 0, 0, 0);
    acc01 = __builtin_amdgcn_mfma_f32_16x16x32_bf16(al0, bh1, acc01, 0, 0, 0);
    acc10 = __builtin_amdgcn_mfma_f32_16x16x32_bf16(ah1, bh0, acc10, 0, 0, 0);
    acc10 = __builtin_amdgcn_mfma_f32_16x16x32_bf16(ah1, bl0, acc10, 0, 0, 0);
    acc10 = __builtin_amdgcn_mfma_f32_16x16x32_bf16(al1, bh0, acc10, 0, 0, 0);
    acc11 = __builtin_amdgcn_mfma_f32_16x16x32_bf16(ah1, bh1, acc11, 0, 0, 0);
    acc11 = __builtin_amdgcn_mfma_f32_16x16x32_bf16(ah1, bl1, acc11, 0, 0, 0);
    acc11 = __builtin_amdgcn_mfma_f32_16x16x32_bf16(al1, bh1, acc11, 0, 0, 0);
  }
  // C layout: col = lane&15, row = (lane>>4)*4 + j
#pragma unroll
  for (int j = 0; j < 4; ++j){
    qi[(size_t)(m0 +  0 + kg * 4 + j) * 1024 + n0 +  0 + r] = acc00[j];
    qi[(size_t)(m0 +  0 + kg * 4 + j) * 1024 + n0 + 16 + r] = acc01[j];
    qi[(size_t)(m0 + 16 + kg * 4 + j) * 1024 + n0 +  0 + r] = acc10[j];
    qi[(size_t)(m0 + 16 + kg * 4 + j) * 1024 + n0 + 16 + r] = acc11[j];
  }
}

// ---------------- kernel 4: q_eff[s,d] = DI^-0.5 * sum_h wgt[s,h]*qi[s,h*64+d] ----------------
__global__ __launch_bounds__(256) void k_qeff(const float* __restrict__ qi,
                                              const float* __restrict__ wgt,
                                              float* __restrict__ qe){
  const int id = blockIdx.x * 256 + threadIdx.x;  // S*64 total
  const int s = id >> 6, d = id & 63;
  float acc = 0.f;
#pragma unroll
  for (int h = 0; h < 16; h++)
    acc = fmaf(wgt[(size_t)s * 16 + h], qi[(size_t)s * 1024 + h * 64 + d], acc);
  qe[(size_t)s * 64 + d] = acc * 0.125f;   // DI^-0.5
}

// ---------------- kernel 5: scores[i,j] = q_eff[i] . ki[j]  (lower-triangular tiles only) ----------------
__global__ __launch_bounds__(256) void k_scores(const float* __restrict__ qe,
                                                const float* __restrict__ ki,
                                                float* __restrict__ sc){
  const int bj = blockIdx.x, bi = blockIdx.y;
  if (bj > bi) return;
  const int t = threadIdx.x;
  const int i0 = bi * 64, j0 = bj * 64;
  __shared__ float Qs[64][68];  // [d][i]
  __shared__ float Ks[64][68];  // [d][j]
#pragma unroll
  for (int u0 = 0; u0 < 4; ++u0){
    int u = t + u0 * 256;
    int r = u >> 4, d4 = u & 15;
    float4 a = *(const float4*)&qe[(size_t)(i0 + r) * 64 + d4 * 4];
    Qs[d4*4+0][r] = a.x; Qs[d4*4+1][r] = a.y; Qs[d4*4+2][r] = a.z; Qs[d4*4+3][r] = a.w;
    float4 b = *(const float4*)&ki[(size_t)(j0 + r) * 64 + d4 * 4];
    Ks[d4*4+0][r] = b.x; Ks[d4*4+1][r] = b.y; Ks[d4*4+2][r] = b.z; Ks[d4*4+3][r] = b.w;
  }
  __syncthreads();
  const int tm = (t & 15) * 4, tn = (t >> 4) * 4;
  float acc[4][4] = {};
#pragma unroll
  for (int d = 0; d < 64; ++d){
    float4 a = *(const float4*)&Qs[d][tm];
    float4 b = *(const float4*)&Ks[d][tn];
    float av[4] = {a.x, a.y, a.z, a.w}, bb[4] = {b.x, b.y, b.z, b.w};
#pragma unroll
    for (int i = 0; i < 4; i++)
#pragma unroll
      for (int j = 0; j < 4; j++) acc[i][j] = fmaf(av[i], bb[j], acc[i][j]);
  }
#pragma unroll
  for (int i = 0; i < 4; i++)
#pragma unroll
    for (int j = 0; j < 4; j++)
      sc[(size_t)(i0 + tm + i) * S + j0 + tn + j] = acc[i][j];
}

// ---------------- kernel 6: per-row causal top-128 via 4-pass radix select ----------------
__global__ __launch_bounds__(256) void k_topk(const float* __restrict__ sc,
                                              int* __restrict__ idx,
                                              int* __restrict__ cnt){
  const int i = blockIdx.x, t = threadIdx.x;
  const int n = i + 1;           // valid causal candidates
  int* outr = idx + (size_t)i * TOPK;
  if (n <= TOPK){
    for (int m = t; m < n; m += 256) outr[m] = m;
    if (t == 0) cnt[i] = n;
    return;
  }
  __shared__ unsigned int keys[S];
  __shared__ int tl[S];
  __shared__ int hist[256];
  __shared__ int ssum[256];
  __shared__ int s_b, s_above, s_gt, s_eq;
  for (int j = t; j < n; j += 256){
    unsigned int u = __float_as_uint(sc[(size_t)i * S + j]);
    keys[j] = (u & 0x80000000u) ? ~u : (u | 0x80000000u);   // order-preserving key
  }
  unsigned int prefix = 0;
  int rem = TOPK;
  for (int p = 3; p >= 0; --p){
    const int sh = p * 8;
    __syncthreads();
    hist[t] = 0;
    __syncthreads();
    const unsigned int himask = (p == 3) ? 0u : (0xFFFFFFFFu << (sh + 8));
    for (int j = t; j < n; j += 256){
      unsigned int kk = keys[j];
      if ((kk & himask) == (prefix & himask)) atomicAdd(&hist[(kk >> sh) & 255], 1);
    }
    __syncthreads();
    // parallel suffix-sum over 256 bins (Hillis-Steele)
    ssum[t] = hist[t];
    __syncthreads();
#pragma unroll
    for (int off = 1; off < 256; off <<= 1){
      int add = (t + off < 256) ? ssum[t + off] : 0;
      __syncthreads();
      ssum[t] += add;
      __syncthreads();
    }
    int excl = ssum[t] - hist[t];          // count of keys in bins > t
    if (excl < rem && excl + hist[t] >= rem){ s_b = t; s_above = excl; }
    __syncthreads();
    prefix |= ((unsigned int)s_b) << sh;
    rem -= s_above;
  }
  if (t == 0){ s_gt = 0; s_eq = 0; }
  __syncthreads();
  for (int j = t; j < n; j += 256){
    unsigned int kk = keys[j];
    if (kk > prefix){ int p = atomicAdd(&s_gt, 1); outr[p] = j; }
    else if (kk == prefix){ int p = atomicAdd(&s_eq, 1); tl[p] = j; }
  }
  __syncthreads();
  const int base = s_gt;          // == TOPK - rem
  if (s_eq == rem){
    for (int m = t; m < rem; m += 256) outr[base + m] = tl[m];
  } else if (t == 0){             // rare exact-tie path: lowest indices first
    int taken = 0;
    for (int j = 0; j < n && taken < rem; ++j)
      if (keys[j] == prefix) outr[base + taken++] = j;
  }
  if (t == 0) cnt[i] = TOPK;
}

// ---------------- kernel 7: gathered sparse attention (bf16 K/V, coalesced) ----------------
__global__ __launch_bounds__(256) void k_attn(const float* __restrict__ q,
                                              const unsigned short* __restrict__ kh,
                                              const unsigned short* __restrict__ vh,
                                              const int* __restrict__ idx,
                                              const int* __restrict__ cnt,
                                              float* __restrict__ out){
  const int i = blockIdx.x;
  const int t = threadIdx.x;
  const int w = t >> 6, l = t & 63;
  const int n = cnt[i];
  const int* irow = idx + (size_t)i * TOPK;

  __shared__ int   sidx[TOPK];
  __shared__ float sq[NH][64];
  __shared__ float sp[NH][TOPK];

  if (t < TOPK) sidx[t] = (t < n) ? irow[t] : 0;
  for (int u = t; u < NH * 64; u += 256)
    sq[u >> 6][u & 63] = q[(size_t)i * (NH * 64) + u] * 0.125f;   // DQK^-0.5
  __syncthreads();

  const int h0 = w * 2, h1 = h0 + 1;

  // ---- QK: 8-lane groups; group g handles key j=pass*8+g; lane covers 8 dims (16B bf16) ----
  const int g  = l >> 3;
  const int gl = l & 7;
  float qa[8], qb[8];
#pragma unroll
  for (int e = 0; e < 8; ++e){ qa[e] = sq[h0][gl * 8 + e]; qb[e] = sq[h1][gl * 8 + e]; }
#pragma unroll 4
  for (int pass = 0; pass < TOPK / 8; ++pass){
    const int j = pass * 8 + g;
    const size_t base = (size_t)sidx[j] * (NH * 64);
    uint4 u0 = *(const uint4*)(kh + base + h0 * 64 + gl * 8);
    uint4 u1 = *(const uint4*)(kh + base + h1 * 64 + gl * 8);
    float d0 = 0.f, d1 = 0.f;
    d0 = fmaf(__uint_as_float(u0.x << 16),         qa[0], d0);
    d0 = fmaf(__uint_as_float(u0.x & 0xFFFF0000u), qa[1], d0);
    d0 = fmaf(__uint_as_float(u0.y << 16),         qa[2], d0);
    d0 = fmaf(__uint_as_float(u0.y & 0xFFFF0000u), qa[3], d0);
    d0 = fmaf(__uint_as_float(u0.z << 16),         qa[4], d0);
    d0 = fmaf(__uint_as_float(u0.z & 0xFFFF0000u), qa[5], d0);
    d0 = fmaf(__uint_as_float(u0.w << 16),         qa[6], d0);
    d0 = fmaf(__uint_as_float(u0.w & 0xFFFF0000u), qa[7], d0);
    d1 = fmaf(__uint_as_float(u1.x << 16),         qb[0], d1);
    d1 = fmaf(__uint_as_float(u1.x & 0xFFFF0000u), qb[1], d1);
    d1 = fmaf(__uint_as_float(u1.y << 16),         qb[2], d1);
    d1 = fmaf(__uint_as_float(u1.y & 0xFFFF0000u), qb[3], d1);
    d1 = fmaf(__uint_as_float(u1.z << 16),         qb[4], d1);
    d1 = fmaf(__uint_as_float(u1.z & 0xFFFF0000u), qb[5], d1);
    d1 = fmaf(__uint_as_float(u1.w << 16),         qb[6], d1);
    d1 = fmaf(__uint_as_float(u1.w & 0xFFFF0000u), qb[7], d1);
#pragma unroll
    for (int o = 1; o < 8; o <<= 1){ d0 += __shfl_xor(d0, o); d1 += __shfl_xor(d1, o); }
    if (gl == 0){ sp[h0][j] = d0; sp[h1][j] = d1; }
  }

  // ---- softmax per head across the wave (2 entries per lane) ----
  const bool v0 = (l < n), v1 = (l + 64 < n);
  {
    float s0 = v0 ? sp[h0][l] : -1e30f, s1 = v1 ? sp[h0][l + 64] : -1e30f;
    float m = wave_max(fmaxf(s0, s1));
    float e0 = v0 ? __expf(s0 - m) : 0.f;
    float e1 = v1 ? __expf(s1 - m) : 0.f;
    float inv = 1.f / wave_sum(e0 + e1);
    sp[h0][l] = e0 * inv;
    sp[h0][l + 64] = e1 * inv;
  }
  {
    float s0 = v0 ? sp[h1][l] : -1e30f, s1 = v1 ? sp[h1][l + 64] : -1e30f;
    float m = wave_max(fmaxf(s0, s1));
    float e0 = v0 ? __expf(s0 - m) : 0.f;
    float e1 = v1 ? __expf(s1 - m) : 0.f;
    float inv = 1.f / wave_sum(e0 + e1);
    sp[h1][l] = e0 * inv;
    sp[h1][l + 64] = e1 * inv;
  }

  // ---- PV: one wave-load covers 2 keys x 2 heads (8B bf16 per lane) ----
  const int j2 = l >> 5;               // key parity
  const int hh = w * 2 + ((l >> 4) & 1);
  const int g4 = l & 15;               // 4 dims
  float o4[4] = {0.f, 0.f, 0.f, 0.f};
#pragma unroll 4
  for (int pass = 0; pass < TOPK / 2; ++pass){
    const int j = pass * 2 + j2;
    const size_t base = (size_t)sidx[j] * (NH * 64);
    ushort4 uv = *(const ushort4*)(vh + base + hh * 64 + g4 * 4);
    float p = sp[hh][j];
    o4[0] = fmaf(p, bf2f(uv.x), o4[0]);
    o4[1] = fmaf(p, bf2f(uv.y), o4[1]);
    o4[2] = fmaf(p, bf2f(uv.z), o4[2]);
    o4[3] = fmaf(p, bf2f(uv.w), o4[3]);
  }
#pragma unroll
  for (int e = 0; e < 4; ++e) o4[e] += __shfl_xor(o4[e], 32);
  if (l < 32)
    *(float4*)&out[((size_t)i * NH + hh) * 64 + g4 * 4] = make_float4(o4[0], o4[1], o4[2], o4[3]);
}

extern "C" void kernel_launch(void* const* d_in, const int* in_sizes, int n_in,
                              void* d_out, int out_size, void* d_ws, size_t ws_size,
                              hipStream_t stream){
  const float* x   = (const float*)d_in[0];
  const float* qin = (const float*)d_in[1];
  const float* q   = (const float*)d_in[2];
  const float* k   = (const float*)d_in[3];
  const float* v   = (const float*)d_in[4];
  const float* wq  = (const float*)d_in[5];
  const float* wk  = (const float*)d_in[6];
  const float* lng = (const float*)d_in[7];
  const float* lnb = (const float*)d_in[8];
  const float* ww  = (const float*)d_in[9];
  float* out = (float*)d_out;

  float* ws   = (float*)d_ws;
  float* part = ws;                  // 4*2048*80   = 655360
  float* ki   = ws + 655360;         // 2048*64     = 131072
  float* wgt  = ws + 786432;         // 2048*16     = 32768
  float* qi   = ws + 819200;         // 2048*1024   = 2097152
  float* qe   = ws + 2916352;        // 2048*64     = 131072
  float* sc   = ws + 3047424;        // 2048*2048   = 4194304
  int*   idx  = (int*)(ws + 7241728);// 2048*128 ints
  int*   cnt  = (int*)(ws + 7503872);// 2048 ints
  // bf16 K/V reuse the qi region (free after k_qeff): 2*1M ushorts = 4 MB < 8 MB
  unsigned short* kh = (unsigned short*)(ws + 819200);
  unsigned short* vh = kh + (size_t)S * NH * 64;
  // split-bf16 staging for the qi GEMM reuses the sc region (free until k_scores):
  // Ah/Al: 2048*512 ushorts each; Bh/Bl (transposed [n][k]): 1024*512 ushorts each = 4 MB total
  unsigned short* Ah = (unsigned short*)sc;
  unsigned short* Al = Ah + (size_t)S * QIN;
  unsigned short* Bh = Al + (size_t)S * QIN;
  unsigned short* Bl = Bh + (size_t)1024 * QIN;

  hipLaunchKernelGGL(k_part,    dim3(4, 32),  dim3(256), 0, stream, x, wk, ww, part);
  hipLaunchKernelGGL(k_lnw,     dim3(2048),   dim3(64),  0, stream, part, lng, lnb, ki, wgt);
  hipLaunchKernelGGL(k_splitA,  dim3(1024),   dim3(256), 0, stream, qin, Ah, Al, S * QIN / 4);
  hipLaunchKernelGGL(k_trsplit, dim3(16, 32), dim3(256), 0, stream, wq, Bh, Bl);
  hipLaunchKernelGGL(k_qi_mfma, dim3(16, 32), dim3(256), 0, stream, Ah, Al, Bh, Bl, qi);
  hipLaunchKernelGGL(k_qeff,    dim3(512),    dim3(256), 0, stream, qi, wgt, qe);
  hipLaunchKernelGGL(k_cvt,     dim3(1024),   dim3(256), 0, stream, k, kh, S * NH * 64 / 4);
  hipLaunchKernelGGL(k_cvt,     dim3(1024),   dim3(256), 0, stream, v, vh, S * NH * 64 / 4);
  hipLaunchKernelGGL(k_scores,  dim3(32, 32), dim3(256), 0, stream, qe, ki, sc);
  hipLaunchKernelGGL(k_topk,    dim3(2048),   dim3(256), 0, stream, sc, idx, cnt);
  hipLaunchKernelGGL(k_attn,    dim3(2048),   dim3(256), 0, stream, q, kh, vh, idx, cnt, out);
}

// Round 6
// 121.284 us; speedup vs baseline: 2.6996x; 1.0837x over previous
//
#include <hip/hip_runtime.h>
#include <hip/hip_bf16.h>
#include <math.h>

#define S 2048
#define DM 1024
#define QIN 512
#define HI 16
#define DI 64
#define NH 8
#define TOPK 128
#define LN_EPS 1e-5f
#define KP 8   // k_part split-K factor

typedef float f32x4 __attribute__((ext_vector_type(4)));
typedef short s16x8 __attribute__((ext_vector_type(8)));

__device__ __forceinline__ float wave_sum(float v){
#pragma unroll
  for (int o = 32; o; o >>= 1) v += __shfl_xor(v, o);
  return v;
}
__device__ __forceinline__ float wave_max(float v){
#pragma unroll
  for (int o = 32; o; o >>= 1) v = fmaxf(v, __shfl_xor(v, o));
  return v;
}
__device__ __forceinline__ unsigned short f2bf(float x){
  unsigned u = __float_as_uint(x);
  unsigned r = u + 0x7FFFu + ((u >> 16) & 1u);   // RN-even
  return (unsigned short)(r >> 16);
}
__device__ __forceinline__ float bf2f(unsigned short s){
  return __uint_as_float(((unsigned)s) << 16);
}

// ---------------- kernel P: fused prep — split-bf16(q_input) + bf16(K) + bf16(V) ----------------
__global__ __launch_bounds__(256) void k_prep(const float* __restrict__ qin,
                                              unsigned short* __restrict__ Ah,
                                              unsigned short* __restrict__ Al,
                                              const float* __restrict__ k,
                                              unsigned short* __restrict__ kh,
                                              const float* __restrict__ v,
                                              unsigned short* __restrict__ vh){
  const int SEG0 = S * QIN / 4;      // 262144
  const int SEG1 = S * NH * 64 / 4;  // 262144
  int id = blockIdx.x * 256 + threadIdx.x;
  if (id < SEG0){
    float4 f = ((const float4*)qin)[id];
    ushort4 h, lo;
    h.x = f2bf(f.x); lo.x = f2bf(f.x - bf2f(h.x));
    h.y = f2bf(f.y); lo.y = f2bf(f.y - bf2f(h.y));
    h.z = f2bf(f.z); lo.z = f2bf(f.z - bf2f(h.z));
    h.w = f2bf(f.w); lo.w = f2bf(f.w - bf2f(h.w));
    ((ushort4*)Ah)[id] = h;
    ((ushort4*)Al)[id] = lo;
  } else if (id < SEG0 + SEG1){
    int j = id - SEG0;
    float4 f = ((const float4*)k)[j];
    ushort4 o;
    o.x = f2bf(f.x); o.y = f2bf(f.y); o.z = f2bf(f.z); o.w = f2bf(f.w);
    ((ushort4*)kh)[j] = o;
  } else {
    int j = id - SEG0 - SEG1;
    float4 f = ((const float4*)v)[j];
    ushort4 o;
    o.x = f2bf(f.x); o.y = f2bf(f.y); o.z = f2bf(f.z); o.w = f2bf(f.w);
    ((ushort4*)vh)[j] = o;
  }
}

// ---------------- kernel 0c: w_q (512x1024) -> transposed split bf16 [n][k] hi/lo ----------------
__global__ __launch_bounds__(256) void k_trsplit(const float* __restrict__ wq,
                                                 unsigned short* __restrict__ bh,
                                                 unsigned short* __restrict__ bl){
  const int k0 = blockIdx.x * 32;   // 16 k-tiles
  const int n0 = blockIdx.y * 32;   // 32 n-tiles
  const int t = threadIdx.x;
  __shared__ unsigned short lh[32][33];
  __shared__ unsigned short ll[32][33];
  const int c = t & 31, r8 = t >> 5;
#pragma unroll
  for (int i = 0; i < 4; ++i){
    int kk = r8 + i * 8;
    float wv = wq[(size_t)(k0 + kk) * 1024 + n0 + c];
    unsigned short h = f2bf(wv);
    lh[c][kk] = h;
    ll[c][kk] = f2bf(wv - bf2f(h));
  }
  __syncthreads();
  const int kk = t & 31, nl = t >> 5;
#pragma unroll
  for (int i = 0; i < 4; ++i){
    int nn = nl + i * 8;
    bh[(size_t)(n0 + nn) * QIN + k0 + kk] = lh[nn][kk];
    bl[(size_t)(n0 + nn) * QIN + k0 + kk] = ll[nn][kk];
  }
}

// ---------------- kernel 1: split-K partial GEMM  x(2048x1024) @ [w_k | w_weights](1024x80) ----------------
__global__ __launch_bounds__(256) void k_part(const float* __restrict__ x,
                                              const float* __restrict__ wk,
                                              const float* __restrict__ ww,
                                              float* __restrict__ part){
  const int kp = blockIdx.x;   // 0..KP-1 (K split)
  const int bm = blockIdx.y;   // 0..31
  const int t  = threadIdx.x;
  const int m0 = bm * 64;
  __shared__ float As[32][68];  // [k][m]
  __shared__ float Bs[32][84];  // [k][n]
  const int tm = (t & 15) * 4;
  const int tn = (t >> 4) * 5;
  float acc[4][5];
#pragma unroll
  for (int i = 0; i < 4; i++)
#pragma unroll
    for (int j = 0; j < 5; j++) acc[i][j] = 0.f;

  for (int kb = 0; kb < (DM / KP) / 32; ++kb){
    const int k0 = kp * (DM / KP) + kb * 32;
#pragma unroll
    for (int i = 0; i < 2; i++){
      int u = t + i * 256;
      int m = u >> 3, c4 = u & 7;
      float4 a = *(const float4*)&x[(size_t)(m0 + m) * DM + k0 + c4 * 4];
      As[c4*4+0][m] = a.x; As[c4*4+1][m] = a.y; As[c4*4+2][m] = a.z; As[c4*4+3][m] = a.w;
    }
#pragma unroll
    for (int i = 0; i < 10; i++){
      int u = t + i * 256;
      int kk = u / 80, nn = u % 80;
      float val = (nn < 64) ? wk[(size_t)(k0 + kk) * 64 + nn]
                            : ww[(size_t)(k0 + kk) * 16 + (nn - 64)];
      Bs[kk][nn] = val;
    }
    __syncthreads();
#pragma unroll
    for (int k = 0; k < 32; ++k){
      float4 a = *(const float4*)&As[k][tm];
      float av[4] = {a.x, a.y, a.z, a.w};
      float bb[5];
#pragma unroll
      for (int j = 0; j < 5; j++) bb[j] = Bs[k][tn + j];
#pragma unroll
      for (int i = 0; i < 4; i++)
#pragma unroll
        for (int j = 0; j < 5; j++) acc[i][j] = fmaf(av[i], bb[j], acc[i][j]);
    }
    __syncthreads();
  }
  float* dst = part + (size_t)kp * S * 80;
#pragma unroll
  for (int i = 0; i < 4; i++)
#pragma unroll
    for (int j = 0; j < 5; j++)
      dst[(size_t)(m0 + tm + i) * 80 + tn + j] = acc[i][j];
}

// ---------------- kernel 2: reduce split-K partials, LayerNorm(ki), scale wgt (4 rows/block) ----------------
__global__ __launch_bounds__(256) void k_lnw(const float* __restrict__ part,
                                             const float* __restrict__ g,
                                             const float* __restrict__ b,
                                             float* __restrict__ ki,
                                             float* __restrict__ wgt){
  const int s = blockIdx.x * 4 + (threadIdx.x >> 6);
  const int l = threadIdx.x & 63;
  float kv = 0.f;
#pragma unroll
  for (int p = 0; p < KP; p++) kv += part[(size_t)p * S * 80 + (size_t)s * 80 + l];
  float wv = 0.f;
  if (l < 16){
#pragma unroll
    for (int p = 0; p < KP; p++) wv += part[(size_t)p * S * 80 + (size_t)s * 80 + 64 + l];
  }
  float mu = wave_sum(kv) * (1.f / 64.f);
  float d  = kv - mu;
  float var = wave_sum(d * d) * (1.f / 64.f);
  float o = d * (1.f / sqrtf(var + LN_EPS)) * g[l] + b[l];
  ki[(size_t)s * 64 + l] = o;
  if (l < 16) wgt[(size_t)s * 16 + l] = wv * 0.25f;   // HI^-0.5
}

// ---------------- kernel 3: qi = q_input @ w_q via split-bf16 MFMA (AhBh + AhBl + AlBh) ----------------
__global__ __launch_bounds__(256) void k_qi_mfma(const unsigned short* __restrict__ Ah,
                                                 const unsigned short* __restrict__ Al,
                                                 const unsigned short* __restrict__ Bh,
                                                 const unsigned short* __restrict__ Bl,
                                                 float* __restrict__ qi){
  const int bn = blockIdx.x;   // 0..15
  const int bm = blockIdx.y;   // 0..31
  const int w = threadIdx.x >> 6, l = threadIdx.x & 63;
  const int m0 = bm * 64 + (w >> 1) * 32;
  const int n0 = bn * 64 + (w & 1) * 32;
  const int r = l & 15, kg = l >> 4;

  f32x4 acc00 = {0,0,0,0}, acc01 = {0,0,0,0}, acc10 = {0,0,0,0}, acc11 = {0,0,0,0};

  const size_t aoff = (size_t)(m0 + r) * QIN + kg * 8;
  const size_t boff = (size_t)(n0 + r) * QIN + kg * 8;
#pragma unroll 4
  for (int k0 = 0; k0 < QIN; k0 += 32){
    s16x8 ah0 = *(const s16x8*)(Ah + aoff + k0);
    s16x8 ah1 = *(const s16x8*)(Ah + aoff + 16 * QIN + k0);
    s16x8 al0 = *(const s16x8*)(Al + aoff + k0);
    s16x8 al1 = *(const s16x8*)(Al + aoff + 16 * QIN + k0);
    s16x8 bh0 = *(const s16x8*)(Bh + boff + k0);
    s16x8 bh1 = *(const s16x8*)(Bh + boff + 16 * QIN + k0);
    s16x8 bl0 = *(const s16x8*)(Bl + boff + k0);
    s16x8 bl1 = *(const s16x8*)(Bl + boff + 16 * QIN + k0);
    acc00 = __builtin_amdgcn_mfma_f32_16x16x32_bf16(ah0, bh0, acc00, 0, 0, 0);
    acc00 = __builtin_amdgcn_mfma_f32_16x16x32_bf16(ah0, bl0, acc00, 0, 0, 0);
    acc00 = __builtin_amdgcn_mfma_f32_16x16x32_bf16(al0, bh0, acc00, 0, 0, 0);
    acc01 = __builtin_amdgcn_mfma_f32_16x16x32_bf16(ah0, bh1, acc01, 0, 0, 0);
    acc01 = __builtin_amdgcn_mfma_f32_16x16x32_bf16(ah0, bl1, acc01, 0, 0, 0);
    acc01 = __builtin_amdgcn_mfma_f32_16x16x32_bf16(al0, bh1, acc01, 0, 0, 0);
    acc10 = __builtin_amdgcn_mfma_f32_16x16x32_bf16(ah1, bh0, acc10, 0, 0, 0);
    acc10 = __builtin_amdgcn_mfma_f32_16x16x32_bf16(ah1, bl0, acc10, 0, 0, 0);
    acc10 = __builtin_amdgcn_mfma_f32_16x16x32_bf16(al1, bh0, acc10, 0, 0, 0);
    acc11 = __builtin_amdgcn_mfma_f32_16x16x32_bf16(ah1, bh1, acc11, 0, 0, 0);
    acc11 = __builtin_amdgcn_mfma_f32_16x16x32_bf16(ah1, bl1, acc11, 0, 0, 0);
    acc11 = __builtin_amdgcn_mfma_f32_16x16x32_bf16(al1, bh1, acc11, 0, 0, 0);
  }
  // C layout: col = lane&15, row = (lane>>4)*4 + j
#pragma unroll
  for (int j = 0; j < 4; ++j){
    qi[(size_t)(m0 +  0 + kg * 4 + j) * 1024 + n0 +  0 + r] = acc00[j];
    qi[(size_t)(m0 +  0 + kg * 4 + j) * 1024 + n0 + 16 + r] = acc01[j];
    qi[(size_t)(m0 + 16 + kg * 4 + j) * 1024 + n0 +  0 + r] = acc10[j];
    qi[(size_t)(m0 + 16 + kg * 4 + j) * 1024 + n0 + 16 + r] = acc11[j];
  }
}

// ---------------- kernel 4: q_eff[s,d] = DI^-0.5 * sum_h wgt[s,h]*qi[s,h*64+d] ----------------
__global__ __launch_bounds__(256) void k_qeff(const float* __restrict__ qi,
                                              const float* __restrict__ wgt,
                                              float* __restrict__ qe){
  const int id = blockIdx.x * 256 + threadIdx.x;  // S*64 total
  const int s = id >> 6, d = id & 63;
  float acc = 0.f;
#pragma unroll
  for (int h = 0; h < 16; h++)
    acc = fmaf(wgt[(size_t)s * 16 + h], qi[(size_t)s * 1024 + h * 64 + d], acc);
  qe[(size_t)s * 64 + d] = acc * 0.125f;   // DI^-0.5
}

// ---------------- kernel 5: scores[i,j] = q_eff[i] . ki[j]  (lower-triangular tiles only) ----------------
__global__ __launch_bounds__(256) void k_scores(const float* __restrict__ qe,
                                                const float* __restrict__ ki,
                                                float* __restrict__ sc){
  const int bj = blockIdx.x, bi = blockIdx.y;
  if (bj > bi) return;
  const int t = threadIdx.x;
  const int i0 = bi * 64, j0 = bj * 64;
  __shared__ float Qs[64][68];  // [d][i]
  __shared__ float Ks[64][68];  // [d][j]
#pragma unroll
  for (int u0 = 0; u0 < 4; ++u0){
    int u = t + u0 * 256;
    int r = u >> 4, d4 = u & 15;
    float4 a = *(const float4*)&qe[(size_t)(i0 + r) * 64 + d4 * 4];
    Qs[d4*4+0][r] = a.x; Qs[d4*4+1][r] = a.y; Qs[d4*4+2][r] = a.z; Qs[d4*4+3][r] = a.w;
    float4 b = *(const float4*)&ki[(size_t)(j0 + r) * 64 + d4 * 4];
    Ks[d4*4+0][r] = b.x; Ks[d4*4+1][r] = b.y; Ks[d4*4+2][r] = b.z; Ks[d4*4+3][r] = b.w;
  }
  __syncthreads();
  const int tm = (t & 15) * 4, tn = (t >> 4) * 4;
  float acc[4][4] = {};
#pragma unroll
  for (int d = 0; d < 64; ++d){
    float4 a = *(const float4*)&Qs[d][tm];
    float4 b = *(const float4*)&Ks[d][tn];
    float av[4] = {a.x, a.y, a.z, a.w}, bb[4] = {b.x, b.y, b.z, b.w};
#pragma unroll
    for (int i = 0; i < 4; i++)
#pragma unroll
      for (int j = 0; j < 4; j++) acc[i][j] = fmaf(av[i], bb[j], acc[i][j]);
  }
#pragma unroll
  for (int i = 0; i < 4; i++)
#pragma unroll
    for (int j = 0; j < 4; j++)
      sc[(size_t)(i0 + tm + i) * S + j0 + tn + j] = acc[i][j];
}

// ---------------- kernel 6: per-row causal top-128, radix select w/ wave-shuffle suffix scan ----------------
__global__ __launch_bounds__(256) void k_topk(const float* __restrict__ sc,
                                              int* __restrict__ idx,
                                              int* __restrict__ cnt){
  const int i = blockIdx.x, t = threadIdx.x;
  const int w = t >> 6, l = t & 63;
  const int n = i + 1;           // valid causal candidates
  int* outr = idx + (size_t)i * TOPK;
  if (n <= TOPK){
    for (int m = t; m < n; m += 256) outr[m] = m;
    if (t == 0) cnt[i] = n;
    return;
  }
  __shared__ unsigned int keys[S];
  __shared__ int tl[S];
  __shared__ int hist[256];
  __shared__ int wtot[4];
  __shared__ int s_b, s_above, s_gt, s_eq;
  hist[t] = 0;
  __syncthreads();
  for (int j = t; j < n; j += 256){
    unsigned int u = __float_as_uint(sc[(size_t)i * S + j]);
    unsigned int kk = (u & 0x80000000u) ? ~u : (u | 0x80000000u);   // order-preserving key
    keys[j] = kk;
    atomicAdd(&hist[kk >> 24], 1);    // pass-3 histogram fused into load loop
  }
  __syncthreads();
  unsigned int prefix = 0;
  int rem = TOPK;
  for (int p = 3; p >= 0; --p){
    const int sh = p * 8;
    // suffix scan of hist via per-wave shuffles (bin = t)
    const int h = hist[t];
    int vsc = h;
#pragma unroll
    for (int off = 1; off < 64; off <<= 1){
      int u = __shfl_down(vsc, off);
      if (l + off < 64) vsc += u;
    }
    if (l == 0) wtot[w] = vsc;
    __syncthreads();
    int later = 0;
#pragma unroll
    for (int ww = 1; ww < 4; ++ww) if (ww > w) later += wtot[ww];
    const int excl = vsc + later - h;       // count of keys in bins > t
    if (excl < rem && excl + h >= rem){ s_b = t; s_above = excl; }
    __syncthreads();
    prefix |= ((unsigned int)s_b) << sh;
    rem -= s_above;
    if (p > 0){
      hist[t] = 0;
      __syncthreads();
      const unsigned int himask = 0xFFFFFFFFu << sh;
      const int shn = sh - 8;
      for (int j = t; j < n; j += 256){
        unsigned int kk = keys[j];
        if ((kk & himask) == prefix) atomicAdd(&hist[(kk >> shn) & 255], 1);
      }
      __syncthreads();
    }
  }
  if (t == 0){ s_gt = 0; s_eq = 0; }
  __syncthreads();
  for (int j = t; j < n; j += 256){
    unsigned int kk = keys[j];
    if (kk > prefix){ int p = atomicAdd(&s_gt, 1); outr[p] = j; }
    else if (kk == prefix){ int p = atomicAdd(&s_eq, 1); tl[p] = j; }
  }
  __syncthreads();
  const int base = s_gt;          // == TOPK - rem
  if (s_eq == rem){
    for (int m = t; m < rem; m += 256) outr[base + m] = tl[m];
  } else if (t == 0){             // rare exact-tie path: lowest indices first
    int taken = 0;
    for (int j = 0; j < n && taken < rem; ++j)
      if (keys[j] == prefix) outr[base + taken++] = j;
  }
  if (t == 0) cnt[i] = TOPK;
}

// ---------------- kernel 7: gathered sparse attention — barrier-free, wave-private LDS ----------------
__global__ __launch_bounds__(256) void k_attn(const float* __restrict__ q,
                                              const unsigned short* __restrict__ kh,
                                              const unsigned short* __restrict__ vh,
                                              const int* __restrict__ idx,
                                              const int* __restrict__ cnt,
                                              float* __restrict__ out){
  const int i = blockIdx.x;
  const int w = threadIdx.x >> 6, l = threadIdx.x & 63;
  const int n = cnt[i];
  const int* irow = idx + (size_t)i * TOPK;

  __shared__ int   sidx[4][TOPK];      // per-wave private copies -> no __syncthreads
  __shared__ float sp[4][2][TOPK];

  sidx[w][l]      = (l < n)      ? irow[l]      : 0;
  sidx[w][l + 64] = (l + 64 < n) ? irow[l + 64] : 0;

  const int h0 = 2 * w, h1 = h0 + 1;
  const int g = l >> 3, gl = l & 7;
  const float* qrow = q + (size_t)i * (NH * 64);
  float qa[8], qb[8];
  {
    float4 a0 = *(const float4*)&qrow[h0 * 64 + gl * 8];
    float4 a1 = *(const float4*)&qrow[h0 * 64 + gl * 8 + 4];
    float4 b0 = *(const float4*)&qrow[h1 * 64 + gl * 8];
    float4 b1 = *(const float4*)&qrow[h1 * 64 + gl * 8 + 4];
    qa[0]=a0.x*0.125f; qa[1]=a0.y*0.125f; qa[2]=a0.z*0.125f; qa[3]=a0.w*0.125f;
    qa[4]=a1.x*0.125f; qa[5]=a1.y*0.125f; qa[6]=a1.z*0.125f; qa[7]=a1.w*0.125f;
    qb[0]=b0.x*0.125f; qb[1]=b0.y*0.125f; qb[2]=b0.z*0.125f; qb[3]=b0.w*0.125f;
    qb[4]=b1.x*0.125f; qb[5]=b1.y*0.125f; qb[6]=b1.z*0.125f; qb[7]=b1.w*0.125f;
  }
  asm volatile("" ::: "memory");

  // ---- QK: 8-lane groups; group g handles key j=pass*8+g; lane covers 8 dims (16B bf16) ----
#pragma unroll 4
  for (int pass = 0; pass < TOPK / 8; ++pass){
    const int j = pass * 8 + g;
    const size_t base = (size_t)sidx[w][j] * (NH * 64);
    uint4 u0 = *(const uint4*)(kh + base + h0 * 64 + gl * 8);
    uint4 u1 = *(const uint4*)(kh + base + h1 * 64 + gl * 8);
    float d0 = 0.f, d1 = 0.f;
    d0 = fmaf(__uint_as_float(u0.x << 16),         qa[0], d0);
    d0 = fmaf(__uint_as_float(u0.x & 0xFFFF0000u), qa[1], d0);
    d0 = fmaf(__uint_as_float(u0.y << 16),         qa[2], d0);
    d0 = fmaf(__uint_as_float(u0.y & 0xFFFF0000u), qa[3], d0);
    d0 = fmaf(__uint_as_float(u0.z << 16),         qa[4], d0);
    d0 = fmaf(__uint_as_float(u0.z & 0xFFFF0000u), qa[5], d0);
    d0 = fmaf(__uint_as_float(u0.w << 16),         qa[6], d0);
    d0 = fmaf(__uint_as_float(u0.w & 0xFFFF0000u), qa[7], d0);
    d1 = fmaf(__uint_as_float(u1.x << 16),         qb[0], d1);
    d1 = fmaf(__uint_as_float(u1.x & 0xFFFF0000u), qb[1], d1);
    d1 = fmaf(__uint_as_float(u1.y << 16),         qb[2], d1);
    d1 = fmaf(__uint_as_float(u1.y & 0xFFFF0000u), qb[3], d1);
    d1 = fmaf(__uint_as_float(u1.z << 16),         qb[4], d1);
    d1 = fmaf(__uint_as_float(u1.z & 0xFFFF0000u), qb[5], d1);
    d1 = fmaf(__uint_as_float(u1.w << 16),         qb[6], d1);
    d1 = fmaf(__uint_as_float(u1.w & 0xFFFF0000u), qb[7], d1);
#pragma unroll
    for (int o = 1; o < 8; o <<= 1){ d0 += __shfl_xor(d0, o); d1 += __shfl_xor(d1, o); }
    if (gl == 0){ sp[w][0][j] = d0; sp[w][1][j] = d1; }
  }
  asm volatile("" ::: "memory");

  // ---- softmax per head across the wave (2 entries per lane); all wave-local ----
  const bool v0 = (l < n), v1 = (l + 64 < n);
  {
    float s0 = v0 ? sp[w][0][l] : -1e30f, s1 = v1 ? sp[w][0][l + 64] : -1e30f;
    float m = wave_max(fmaxf(s0, s1));
    float e0 = v0 ? __expf(s0 - m) : 0.f;
    float e1 = v1 ? __expf(s1 - m) : 0.f;
    float inv = 1.f / wave_sum(e0 + e1);
    sp[w][0][l] = e0 * inv;
    sp[w][0][l + 64] = e1 * inv;
  }
  {
    float s0 = v0 ? sp[w][1][l] : -1e30f, s1 = v1 ? sp[w][1][l + 64] : -1e30f;
    float m = wave_max(fmaxf(s0, s1));
    float e0 = v0 ? __expf(s0 - m) : 0.f;
    float e1 = v1 ? __expf(s1 - m) : 0.f;
    float inv = 1.f / wave_sum(e0 + e1);
    sp[w][1][l] = e0 * inv;
    sp[w][1][l + 64] = e1 * inv;
  }
  asm volatile("" ::: "memory");

  // ---- PV: one wave-load covers 2 keys x 2 heads (8B bf16 per lane) ----
  const int j2 = l >> 5;               // key parity
  const int hp = (l >> 4) & 1;         // head parity within wave
  const int hh = h0 + hp;
  const int g4 = l & 15;               // 4 dims
  float o4[4] = {0.f, 0.f, 0.f, 0.f};
#pragma unroll 4
  for (int pass = 0; pass < TOPK / 2; ++pass){
    const int j = pass * 2 + j2;
    const size_t base = (size_t)sidx[w][j] * (NH * 64);
    ushort4 uv = *(const ushort4*)(vh + base + hh * 64 + g4 * 4);
    float p = sp[w][hp][j];
    o4[0] = fmaf(p, bf2f(uv.x), o4[0]);
    o4[1] = fmaf(p, bf2f(uv.y), o4[1]);
    o4[2] = fmaf(p, bf2f(uv.z), o4[2]);
    o4[3] = fmaf(p, bf2f(uv.w), o4[3]);
  }
#pragma unroll
  for (int e = 0; e < 4; ++e) o4[e] += __shfl_xor(o4[e], 32);
  if (l < 32)
    *(float4*)&out[((size_t)i * NH + hh) * 64 + g4 * 4] = make_float4(o4[0], o4[1], o4[2], o4[3]);
}

extern "C" void kernel_launch(void* const* d_in, const int* in_sizes, int n_in,
                              void* d_out, int out_size, void* d_ws, size_t ws_size,
                              hipStream_t stream){
  const float* x   = (const float*)d_in[0];
  const float* qin = (const float*)d_in[1];
  const float* q   = (const float*)d_in[2];
  const float* k   = (const float*)d_in[3];
  const float* v   = (const float*)d_in[4];
  const float* wq  = (const float*)d_in[5];
  const float* wk  = (const float*)d_in[6];
  const float* lng = (const float*)d_in[7];
  const float* lnb = (const float*)d_in[8];
  const float* ww  = (const float*)d_in[9];
  float* out = (float*)d_out;

  float* ws   = (float*)d_ws;
  float* part = ws;                         // KP*2048*80 = 1,310,720
  float* ki   = ws + 1310720;               // 131072
  float* wgt  = ws + 1441792;               // 32768
  float* qi   = ws + 1474560;               // 2,097,152
  float* qe   = ws + 3571712;               // 131072
  float* sc   = ws + 3702784;               // 4,194,304
  int*   idx  = (int*)(ws + 7897088);       // 262144 ints
  int*   cnt  = (int*)(ws + 8159232);       // 2048 ints
  // bf16 K/V reuse the part region (dead after k_lnw): 2*1,048,576 ushorts = 1,048,576 floats
  unsigned short* kh = (unsigned short*)part;
  unsigned short* vh = kh + (size_t)S * NH * 64;
  // split-bf16 staging for qi GEMM reuses sc region (dead until k_scores)
  unsigned short* Ah = (unsigned short*)sc;
  unsigned short* Al = Ah + (size_t)S * QIN;
  unsigned short* Bh = Al + (size_t)S * QIN;
  unsigned short* Bl = Bh + (size_t)1024 * QIN;

  hipLaunchKernelGGL(k_part,    dim3(KP, 32), dim3(256), 0, stream, x, wk, ww, part);
  hipLaunchKernelGGL(k_lnw,     dim3(512),    dim3(256), 0, stream, part, lng, lnb, ki, wgt);
  hipLaunchKernelGGL(k_prep,    dim3(3072),   dim3(256), 0, stream, qin, Ah, Al, k, kh, v, vh);
  hipLaunchKernelGGL(k_trsplit, dim3(16, 32), dim3(256), 0, stream, wq, Bh, Bl);
  hipLaunchKernelGGL(k_qi_mfma, dim3(16, 32), dim3(256), 0, stream, Ah, Al, Bh, Bl, qi);
  hipLaunchKernelGGL(k_qeff,    dim3(512),    dim3(256), 0, stream, qi, wgt, qe);
  hipLaunchKernelGGL(k_scores,  dim3(32, 32), dim3(256), 0, stream, qe, ki, sc);
  hipLaunchKernelGGL(k_topk,    dim3(2048),   dim3(256), 0, stream, sc, idx, cnt);
  hipLaunchKernelGGL(k_attn,    dim3(2048),   dim3(256), 0, stream, q, kh, vh, idx, cnt, out);
}

// Round 7
// 120.131 us; speedup vs baseline: 2.7255x; 1.0096x over previous
//
#include <hip/hip_runtime.h>
#include <hip/hip_bf16.h>
#include <hip/hip_fp16.h>
#include <math.h>

#define S 2048
#define DM 1024
#define QIN 512
#define HI 16
#define DI 64
#define NH 8
#define TOPK 128
#define LN_EPS 1e-5f
#define KP 8   // k_part split-K factor

typedef float f32x4 __attribute__((ext_vector_type(4)));
typedef short s16x8 __attribute__((ext_vector_type(8)));

__device__ __forceinline__ float wave_sum(float v){
#pragma unroll
  for (int o = 32; o; o >>= 1) v += __shfl_xor(v, o);
  return v;
}
__device__ __forceinline__ float wave_max(float v){
#pragma unroll
  for (int o = 32; o; o >>= 1) v = fmaxf(v, __shfl_xor(v, o));
  return v;
}
__device__ __forceinline__ unsigned short f2bf(float x){
  unsigned u = __float_as_uint(x);
  unsigned r = u + 0x7FFFu + ((u >> 16) & 1u);   // RN-even
  return (unsigned short)(r >> 16);
}
__device__ __forceinline__ float bf2f(unsigned short s){
  return __uint_as_float(((unsigned)s) << 16);
}
__device__ __forceinline__ unsigned short f2h(float x){
  return __half_as_ushort(__float2half_rn(x));
}
union UH2 { unsigned int u; __half2 h; };
__device__ __forceinline__ __half2 as_half2(unsigned int u){ UH2 x; x.u = u; return x.h; }

// ---------------- kernel P: fused prep — split-bf16(q_input) + f16(K,V) + trsplit(w_q) ----------------
__global__ __launch_bounds__(256) void k_prep(const float* __restrict__ qin,
                                              unsigned short* __restrict__ Ah,
                                              unsigned short* __restrict__ Al,
                                              const float* __restrict__ k,
                                              unsigned short* __restrict__ kh,
                                              const float* __restrict__ v,
                                              unsigned short* __restrict__ vh,
                                              const float* __restrict__ wq,
                                              unsigned short* __restrict__ Bh,
                                              unsigned short* __restrict__ Bl){
  __shared__ unsigned short lh[32][33];
  __shared__ unsigned short ll[32][33];
  const int SEG0 = S * QIN / 4;      // 262144
  const int SEG1 = S * NH * 64 / 4;  // 262144
  const int bid = blockIdx.x;
  if (bid < 3072){
    int id = bid * 256 + threadIdx.x;
    if (id < SEG0){
      float4 f = ((const float4*)qin)[id];
      ushort4 h, lo;
      h.x = f2bf(f.x); lo.x = f2bf(f.x - bf2f(h.x));
      h.y = f2bf(f.y); lo.y = f2bf(f.y - bf2f(h.y));
      h.z = f2bf(f.z); lo.z = f2bf(f.z - bf2f(h.z));
      h.w = f2bf(f.w); lo.w = f2bf(f.w - bf2f(h.w));
      ((ushort4*)Ah)[id] = h;
      ((ushort4*)Al)[id] = lo;
    } else if (id < SEG0 + SEG1){
      int j = id - SEG0;
      float4 f = ((const float4*)k)[j];
      ushort4 o;
      o.x = f2h(f.x); o.y = f2h(f.y); o.z = f2h(f.z); o.w = f2h(f.w);
      ((ushort4*)kh)[j] = o;
    } else {
      int j = id - SEG0 - SEG1;
      float4 f = ((const float4*)v)[j];
      ushort4 o;
      o.x = f2h(f.x); o.y = f2h(f.y); o.z = f2h(f.z); o.w = f2h(f.w);
      ((ushort4*)vh)[j] = o;
    }
    return;
  }
  // ---- trsplit part: w_q (512x1024) -> transposed split bf16 [n][k] hi/lo ----
  const int b2 = bid - 3072;          // 0..511
  const int k0 = (b2 & 15) * 32;
  const int n0 = (b2 >> 4) * 32;
  const int t = threadIdx.x;
  const int c = t & 31, r8 = t >> 5;
#pragma unroll
  for (int i = 0; i < 4; ++i){
    int kk = r8 + i * 8;
    float wv = wq[(size_t)(k0 + kk) * 1024 + n0 + c];
    unsigned short h = f2bf(wv);
    lh[c][kk] = h;
    ll[c][kk] = f2bf(wv - bf2f(h));
  }
  __syncthreads();
  const int kk = t & 31, nl = t >> 5;
#pragma unroll
  for (int i = 0; i < 4; ++i){
    int nn = nl + i * 8;
    Bh[(size_t)(n0 + nn) * QIN + k0 + kk] = lh[nn][kk];
    Bl[(size_t)(n0 + nn) * QIN + k0 + kk] = ll[nn][kk];
  }
}

// ---------------- kernel 1: split-K partial GEMM  x(2048x1024) @ [w_k | w_weights](1024x80) ----------------
__global__ __launch_bounds__(256) void k_part(const float* __restrict__ x,
                                              const float* __restrict__ wk,
                                              const float* __restrict__ ww,
                                              float* __restrict__ part){
  const int kp = blockIdx.x;   // 0..KP-1 (K split)
  const int bm = blockIdx.y;   // 0..31
  const int t  = threadIdx.x;
  const int m0 = bm * 64;
  __shared__ float As[32][68];  // [k][m]
  __shared__ float Bs[32][84];  // [k][n]
  const int tm = (t & 15) * 4;
  const int tn = (t >> 4) * 5;
  float acc[4][5];
#pragma unroll
  for (int i = 0; i < 4; i++)
#pragma unroll
    for (int j = 0; j < 5; j++) acc[i][j] = 0.f;

  for (int kb = 0; kb < (DM / KP) / 32; ++kb){
    const int k0 = kp * (DM / KP) + kb * 32;
#pragma unroll
    for (int i = 0; i < 2; i++){
      int u = t + i * 256;
      int m = u >> 3, c4 = u & 7;
      float4 a = *(const float4*)&x[(size_t)(m0 + m) * DM + k0 + c4 * 4];
      As[c4*4+0][m] = a.x; As[c4*4+1][m] = a.y; As[c4*4+2][m] = a.z; As[c4*4+3][m] = a.w;
    }
#pragma unroll
    for (int i = 0; i < 10; i++){
      int u = t + i * 256;
      int kk = u / 80, nn = u % 80;
      float val = (nn < 64) ? wk[(size_t)(k0 + kk) * 64 + nn]
                            : ww[(size_t)(k0 + kk) * 16 + (nn - 64)];
      Bs[kk][nn] = val;
    }
    __syncthreads();
#pragma unroll
    for (int k = 0; k < 32; ++k){
      float4 a = *(const float4*)&As[k][tm];
      float av[4] = {a.x, a.y, a.z, a.w};
      float bb[5];
#pragma unroll
      for (int j = 0; j < 5; j++) bb[j] = Bs[k][tn + j];
#pragma unroll
      for (int i = 0; i < 4; i++)
#pragma unroll
        for (int j = 0; j < 5; j++) acc[i][j] = fmaf(av[i], bb[j], acc[i][j]);
    }
    __syncthreads();
  }
  float* dst = part + (size_t)kp * S * 80;
#pragma unroll
  for (int i = 0; i < 4; i++)
#pragma unroll
    for (int j = 0; j < 5; j++)
      dst[(size_t)(m0 + tm + i) * 80 + tn + j] = acc[i][j];
}

// ---------------- kernel 2: reduce split-K partials, LayerNorm(ki), scale wgt (4 rows/block) ----------------
__global__ __launch_bounds__(256) void k_lnw(const float* __restrict__ part,
                                             const float* __restrict__ g,
                                             const float* __restrict__ b,
                                             float* __restrict__ ki,
                                             float* __restrict__ wgt){
  const int s = blockIdx.x * 4 + (threadIdx.x >> 6);
  const int l = threadIdx.x & 63;
  float kv = 0.f;
#pragma unroll
  for (int p = 0; p < KP; p++) kv += part[(size_t)p * S * 80 + (size_t)s * 80 + l];
  float wv = 0.f;
  if (l < 16){
#pragma unroll
    for (int p = 0; p < KP; p++) wv += part[(size_t)p * S * 80 + (size_t)s * 80 + 64 + l];
  }
  float mu = wave_sum(kv) * (1.f / 64.f);
  float d  = kv - mu;
  float var = wave_sum(d * d) * (1.f / 64.f);
  float o = d * (1.f / sqrtf(var + LN_EPS)) * g[l] + b[l];
  ki[(size_t)s * 64 + l] = o;
  if (l < 16) wgt[(size_t)s * 16 + l] = wv * 0.25f;   // HI^-0.5
}

// ---------------- kernel 3: qi = q_input @ w_q via split-bf16 MFMA (AhBh + AhBl + AlBh) ----------------
__global__ __launch_bounds__(256) void k_qi_mfma(const unsigned short* __restrict__ Ah,
                                                 const unsigned short* __restrict__ Al,
                                                 const unsigned short* __restrict__ Bh,
                                                 const unsigned short* __restrict__ Bl,
                                                 float* __restrict__ qi){
  const int bn = blockIdx.x;   // 0..15
  const int bm = blockIdx.y;   // 0..31
  const int w = threadIdx.x >> 6, l = threadIdx.x & 63;
  const int m0 = bm * 64 + (w >> 1) * 32;
  const int n0 = bn * 64 + (w & 1) * 32;
  const int r = l & 15, kg = l >> 4;

  f32x4 acc00 = {0,0,0,0}, acc01 = {0,0,0,0}, acc10 = {0,0,0,0}, acc11 = {0,0,0,0};

  const size_t aoff = (size_t)(m0 + r) * QIN + kg * 8;
  const size_t boff = (size_t)(n0 + r) * QIN + kg * 8;
#pragma unroll 4
  for (int k0 = 0; k0 < QIN; k0 += 32){
    s16x8 ah0 = *(const s16x8*)(Ah + aoff + k0);
    s16x8 ah1 = *(const s16x8*)(Ah + aoff + 16 * QIN + k0);
    s16x8 al0 = *(const s16x8*)(Al + aoff + k0);
    s16x8 al1 = *(const s16x8*)(Al + aoff + 16 * QIN + k0);
    s16x8 bh0 = *(const s16x8*)(Bh + boff + k0);
    s16x8 bh1 = *(const s16x8*)(Bh + boff + 16 * QIN + k0);
    s16x8 bl0 = *(const s16x8*)(Bl + boff + k0);
    s16x8 bl1 = *(const s16x8*)(Bl + boff + 16 * QIN + k0);
    acc00 = __builtin_amdgcn_mfma_f32_16x16x32_bf16(ah0, bh0, acc00, 0, 0, 0);
    acc00 = __builtin_amdgcn_mfma_f32_16x16x32_bf16(ah0, bl0, acc00, 0, 0, 0);
    acc00 = __builtin_amdgcn_mfma_f32_16x16x32_bf16(al0, bh0, acc00, 0, 0, 0);
    acc01 = __builtin_amdgcn_mfma_f32_16x16x32_bf16(ah0, bh1, acc01, 0, 0, 0);
    acc01 = __builtin_amdgcn_mfma_f32_16x16x32_bf16(ah0, bl1, acc01, 0, 0, 0);
    acc01 = __builtin_amdgcn_mfma_f32_16x16x32_bf16(al0, bh1, acc01, 0, 0, 0);
    acc10 = __builtin_amdgcn_mfma_f32_16x16x32_bf16(ah1, bh0, acc10, 0, 0, 0);
    acc10 = __builtin_amdgcn_mfma_f32_16x16x32_bf16(ah1, bl0, acc10, 0, 0, 0);
    acc10 = __builtin_amdgcn_mfma_f32_16x16x32_bf16(al1, bh0, acc10, 0, 0, 0);
    acc11 = __builtin_amdgcn_mfma_f32_16x16x32_bf16(ah1, bh1, acc11, 0, 0, 0);
    acc11 = __builtin_amdgcn_mfma_f32_16x16x32_bf16(ah1, bl1, acc11, 0, 0, 0);
    acc11 = __builtin_amdgcn_mfma_f32_16x16x32_bf16(al1, bh1, acc11, 0, 0, 0);
  }
  // C layout: col = lane&15, row = (lane>>4)*4 + j
#pragma unroll
  for (int j = 0; j < 4; ++j){
    qi[(size_t)(m0 +  0 + kg * 4 + j) * 1024 + n0 +  0 + r] = acc00[j];
    qi[(size_t)(m0 +  0 + kg * 4 + j) * 1024 + n0 + 16 + r] = acc01[j];
    qi[(size_t)(m0 + 16 + kg * 4 + j) * 1024 + n0 +  0 + r] = acc10[j];
    qi[(size_t)(m0 + 16 + kg * 4 + j) * 1024 + n0 + 16 + r] = acc11[j];
  }
}

// ---------------- kernel 4: q_eff[s,d] = DI^-0.5 * sum_h wgt[s,h]*qi[s,h*64+d] ----------------
__global__ __launch_bounds__(256) void k_qeff(const float* __restrict__ qi,
                                              const float* __restrict__ wgt,
                                              float* __restrict__ qe){
  const int id = blockIdx.x * 256 + threadIdx.x;  // S*64 total
  const int s = id >> 6, d = id & 63;
  float acc = 0.f;
#pragma unroll
  for (int h = 0; h < 16; h++)
    acc = fmaf(wgt[(size_t)s * 16 + h], qi[(size_t)s * 1024 + h * 64 + d], acc);
  qe[(size_t)s * 64 + d] = acc * 0.125f;   // DI^-0.5
}

// ---------------- kernel 5: scores[i,j] = q_eff[i] . ki[j]  (lower-triangular tiles only) ----------------
__global__ __launch_bounds__(256) void k_scores(const float* __restrict__ qe,
                                                const float* __restrict__ ki,
                                                float* __restrict__ sc){
  const int bj = blockIdx.x, bi = blockIdx.y;
  if (bj > bi) return;
  const int t = threadIdx.x;
  const int i0 = bi * 64, j0 = bj * 64;
  __shared__ float Qs[64][68];  // [d][i]
  __shared__ float Ks[64][68];  // [d][j]
#pragma unroll
  for (int u0 = 0; u0 < 4; ++u0){
    int u = t + u0 * 256;
    int r = u >> 4, d4 = u & 15;
    float4 a = *(const float4*)&qe[(size_t)(i0 + r) * 64 + d4 * 4];
    Qs[d4*4+0][r] = a.x; Qs[d4*4+1][r] = a.y; Qs[d4*4+2][r] = a.z; Qs[d4*4+3][r] = a.w;
    float4 b = *(const float4*)&ki[(size_t)(j0 + r) * 64 + d4 * 4];
    Ks[d4*4+0][r] = b.x; Ks[d4*4+1][r] = b.y; Ks[d4*4+2][r] = b.z; Ks[d4*4+3][r] = b.w;
  }
  __syncthreads();
  const int tm = (t & 15) * 4, tn = (t >> 4) * 4;
  float acc[4][4] = {};
#pragma unroll
  for (int d = 0; d < 64; ++d){
    float4 a = *(const float4*)&Qs[d][tm];
    float4 b = *(const float4*)&Ks[d][tn];
    float av[4] = {a.x, a.y, a.z, a.w}, bb[4] = {b.x, b.y, b.z, b.w};
#pragma unroll
    for (int i = 0; i < 4; i++)
#pragma unroll
      for (int j = 0; j < 4; j++) acc[i][j] = fmaf(av[i], bb[j], acc[i][j]);
  }
#pragma unroll
  for (int i = 0; i < 4; i++)
#pragma unroll
    for (int j = 0; j < 4; j++)
      sc[(size_t)(i0 + tm + i) * S + j0 + tn + j] = acc[i][j];
}

// ---------------- kernel 6: per-row causal top-128 — radix select with candidate compaction ----------------
__global__ __launch_bounds__(256) void k_topk(const float* __restrict__ sc,
                                              int* __restrict__ idx,
                                              int* __restrict__ cnt){
  const int i = blockIdx.x, t = threadIdx.x;
  const int w = t >> 6, l = t & 63;
  const int n = i + 1;           // valid causal candidates
  int* outr = idx + (size_t)i * TOPK;
  if (n <= TOPK){
    for (int m = t; m < n; m += 256) outr[m] = m;
    if (t == 0) cnt[i] = n;
    return;
  }
  __shared__ unsigned int keys[S];
  __shared__ int lA[S];
  __shared__ int lB[S];
  __shared__ int hist[256];
  __shared__ int wtot[4];
  __shared__ int s_b, s_above, s_out, s_m;
  hist[t] = 0;
  if (t == 0) s_out = 0;
  __syncthreads();
  for (int j = t; j < n; j += 256){
    unsigned int u = __float_as_uint(sc[(size_t)i * S + j]);
    unsigned int kk = (u & 0x80000000u) ? ~u : (u | 0x80000000u);   // order-preserving key
    keys[j] = kk;
    atomicAdd(&hist[kk >> 24], 1);    // top-byte histogram fused into load
  }
  __syncthreads();
  int rem = TOPK;
  // ---- pass 3: pick top-byte boundary bucket ----
  {
    const int h = hist[t];
    int vsc = h;
#pragma unroll
    for (int off = 1; off < 64; off <<= 1){
      int u = __shfl_down(vsc, off);
      if (l + off < 64) vsc += u;
    }
    if (l == 0) wtot[w] = vsc;
    __syncthreads();
    int later = 0;
#pragma unroll
    for (int ww = 1; ww < 4; ++ww) if (ww > w) later += wtot[ww];
    const int excl = vsc + later - h;
    if (excl < rem && excl + h >= rem){ s_b = t; s_above = excl; }
    __syncthreads();
  }
  int b = s_b;
  rem -= s_above;
  if (t == 0) s_m = 0;
  __syncthreads();
  // ---- single pass: emit definite-ins, compact boundary bucket ----
  for (int j = t; j < n; j += 256){
    int by = keys[j] >> 24;
    if (by > b){ int p = atomicAdd(&s_out, 1); outr[p] = j; }
    else if (by == b){ int p = atomicAdd(&s_m, 1); lA[p] = j; }
  }
  __syncthreads();
  int m = s_m;
  int* Lsrc = lA; int* Ldst = lB;
  bool done = false;
  if (m == rem){
    int base = TOPK - rem;
    for (int u = t; u < m; u += 256) outr[base + u] = Lsrc[u];
    done = true;
  }
  // ---- refine on compacted list (typically 30-300 entries) ----
  for (int p = 2; p >= 0 && !done; --p){
    const int sh = p * 8;
    __syncthreads();
    hist[t] = 0;
    __syncthreads();
    for (int u = t; u < m; u += 256) atomicAdd(&hist[(keys[Lsrc[u]] >> sh) & 255], 1);
    __syncthreads();
    {
      const int h = hist[t];
      int vsc = h;
#pragma unroll
      for (int off = 1; off < 64; off <<= 1){
        int u = __shfl_down(vsc, off);
        if (l + off < 64) vsc += u;
      }
      if (l == 0) wtot[w] = vsc;
      __syncthreads();
      int later = 0;
#pragma unroll
      for (int ww = 1; ww < 4; ++ww) if (ww > w) later += wtot[ww];
      const int excl = vsc + later - h;
      if (excl < rem && excl + h >= rem){ s_b = t; s_above = excl; }
      __syncthreads();
    }
    b = s_b;
    rem -= s_above;
    if (t == 0) s_m = 0;
    __syncthreads();
    for (int u = t; u < m; u += 256){
      int j = Lsrc[u]; int by = (keys[j] >> sh) & 255;
      if (by > b){ int p2 = atomicAdd(&s_out, 1); outr[p2] = j; }
      else if (by == b){ int p2 = atomicAdd(&s_m, 1); Ldst[p2] = j; }
    }
    __syncthreads();
    m = s_m;
    { int* tmp = Lsrc; Lsrc = Ldst; Ldst = tmp; }
    if (m == rem){
      int base = TOPK - rem;
      for (int u = t; u < m; u += 256) outr[base + u] = Lsrc[u];
      done = true;
    }
  }
  if (!done && t == 0){
    // exact 32-bit ties: take rem lowest indices (rare)
    int base = TOPK - rem;
    for (int a = 0; a < rem; ++a){
      int mn = 1 << 30, pos = -1;
      for (int u = 0; u < m; ++u){ int j = Lsrc[u]; if (j < mn){ mn = j; pos = u; } }
      outr[base + a] = mn; Lsrc[pos] = 1 << 30;
    }
  }
  if (t == 0) cnt[i] = TOPK;
}

// ---------------- kernel 7: gathered sparse attention — f16 K/V, packed-fma QK, barrier-free ----------------
__global__ __launch_bounds__(256) void k_attn(const float* __restrict__ q,
                                              const unsigned short* __restrict__ kh,
                                              const unsigned short* __restrict__ vh,
                                              const int* __restrict__ idx,
                                              const int* __restrict__ cnt,
                                              float* __restrict__ out){
  const int i = blockIdx.x;
  const int w = threadIdx.x >> 6, l = threadIdx.x & 63;
  const int n = cnt[i];
  const int* irow = idx + (size_t)i * TOPK;

  __shared__ int   sidx[4][TOPK];      // per-wave private copies -> no __syncthreads
  __shared__ float sp[4][2][TOPK];

  sidx[w][l]      = (l < n)      ? irow[l]      : 0;
  sidx[w][l + 64] = (l + 64 < n) ? irow[l + 64] : 0;

  const int h0 = 2 * w, h1 = h0 + 1;
  const int g = l >> 3, gl = l & 7;
  const float* qrow = q + (size_t)i * (NH * 64);
  __half2 qa2[4], qb2[4];
  {
    float4 a0 = *(const float4*)&qrow[h0 * 64 + gl * 8];
    float4 a1 = *(const float4*)&qrow[h0 * 64 + gl * 8 + 4];
    float4 b0 = *(const float4*)&qrow[h1 * 64 + gl * 8];
    float4 b1 = *(const float4*)&qrow[h1 * 64 + gl * 8 + 4];
    qa2[0] = __floats2half2_rn(a0.x * 0.125f, a0.y * 0.125f);
    qa2[1] = __floats2half2_rn(a0.z * 0.125f, a0.w * 0.125f);
    qa2[2] = __floats2half2_rn(a1.x * 0.125f, a1.y * 0.125f);
    qa2[3] = __floats2half2_rn(a1.z * 0.125f, a1.w * 0.125f);
    qb2[0] = __floats2half2_rn(b0.x * 0.125f, b0.y * 0.125f);
    qb2[1] = __floats2half2_rn(b0.z * 0.125f, b0.w * 0.125f);
    qb2[2] = __floats2half2_rn(b1.x * 0.125f, b1.y * 0.125f);
    qb2[3] = __floats2half2_rn(b1.z * 0.125f, b1.w * 0.125f);
  }
  asm volatile("" ::: "memory");

  // ---- QK: 8-lane groups; group g handles key j=pass*8+g; lane covers 8 dims via packed f16 fma ----
#pragma unroll 4
  for (int pass = 0; pass < TOPK / 8; ++pass){
    const int j = pass * 8 + g;
    const size_t base = (size_t)sidx[w][j] * (NH * 64);
    uint4 u0 = *(const uint4*)(kh + base + h0 * 64 + gl * 8);
    uint4 u1 = *(const uint4*)(kh + base + h1 * 64 + gl * 8);
    __half2 acc0 = __floats2half2_rn(0.f, 0.f);
    __half2 acc1 = __floats2half2_rn(0.f, 0.f);
    acc0 = __hfma2(as_half2(u0.x), qa2[0], acc0);
    acc0 = __hfma2(as_half2(u0.y), qa2[1], acc0);
    acc0 = __hfma2(as_half2(u0.z), qa2[2], acc0);
    acc0 = __hfma2(as_half2(u0.w), qa2[3], acc0);
    acc1 = __hfma2(as_half2(u1.x), qb2[0], acc1);
    acc1 = __hfma2(as_half2(u1.y), qb2[1], acc1);
    acc1 = __hfma2(as_half2(u1.z), qb2[2], acc1);
    acc1 = __hfma2(as_half2(u1.w), qb2[3], acc1);
    float d0 = __low2float(acc0) + __high2float(acc0);
    float d1 = __low2float(acc1) + __high2float(acc1);
#pragma unroll
    for (int o = 1; o < 8; o <<= 1){ d0 += __shfl_xor(d0, o); d1 += __shfl_xor(d1, o); }
    if (gl == 0){ sp[w][0][j] = d0; sp[w][1][j] = d1; }
  }
  asm volatile("" ::: "memory");

  // ---- softmax per head across the wave (2 entries per lane); all wave-local ----
  const bool v0 = (l < n), v1 = (l + 64 < n);
  {
    float s0 = v0 ? sp[w][0][l] : -1e30f, s1 = v1 ? sp[w][0][l + 64] : -1e30f;
    float m = wave_max(fmaxf(s0, s1));
    float e0 = v0 ? __expf(s0 - m) : 0.f;
    float e1 = v1 ? __expf(s1 - m) : 0.f;
    float inv = 1.f / wave_sum(e0 + e1);
    sp[w][0][l] = e0 * inv;
    sp[w][0][l + 64] = e1 * inv;
  }
  {
    float s0 = v0 ? sp[w][1][l] : -1e30f, s1 = v1 ? sp[w][1][l + 64] : -1e30f;
    float m = wave_max(fmaxf(s0, s1));
    float e0 = v0 ? __expf(s0 - m) : 0.f;
    float e1 = v1 ? __expf(s1 - m) : 0.f;
    float inv = 1.f / wave_sum(e0 + e1);
    sp[w][1][l] = e0 * inv;
    sp[w][1][l + 64] = e1 * inv;
  }
  asm volatile("" ::: "memory");

  // ---- PV: one wave-load covers 2 keys x 2 heads (8B f16 per lane) ----
  const int j2 = l >> 5;               // key parity
  const int hp = (l >> 4) & 1;         // head parity within wave
  const int hh = h0 + hp;
  const int g4 = l & 15;               // 4 dims
  float o4[4] = {0.f, 0.f, 0.f, 0.f};
#pragma unroll 4
  for (int pass = 0; pass < TOPK / 2; ++pass){
    const int j = pass * 2 + j2;
    const size_t base = (size_t)sidx[w][j] * (NH * 64);
    uint2 uv = *(const uint2*)(vh + base + hh * 64 + g4 * 4);
    __half2 v01 = as_half2(uv.x), v23 = as_half2(uv.y);
    float p = sp[w][hp][j];
    o4[0] = fmaf(p, __low2float(v01),  o4[0]);
    o4[1] = fmaf(p, __high2float(v01), o4[1]);
    o4[2] = fmaf(p, __low2float(v23),  o4[2]);
    o4[3] = fmaf(p, __high2float(v23), o4[3]);
  }
#pragma unroll
  for (int e = 0; e < 4; ++e) o4[e] += __shfl_xor(o4[e], 32);
  if (l < 32)
    *(float4*)&out[((size_t)i * NH + hh) * 64 + g4 * 4] = make_float4(o4[0], o4[1], o4[2], o4[3]);
}

extern "C" void kernel_launch(void* const* d_in, const int* in_sizes, int n_in,
                              void* d_out, int out_size, void* d_ws, size_t ws_size,
                              hipStream_t stream){
  const float* x   = (const float*)d_in[0];
  const float* qin = (const float*)d_in[1];
  const float* q   = (const float*)d_in[2];
  const float* k   = (const float*)d_in[3];
  const float* v   = (const float*)d_in[4];
  const float* wq  = (const float*)d_in[5];
  const float* wk  = (const float*)d_in[6];
  const float* lng = (const float*)d_in[7];
  const float* lnb = (const float*)d_in[8];
  const float* ww  = (const float*)d_in[9];
  float* out = (float*)d_out;

  float* ws   = (float*)d_ws;
  float* part = ws;                         // KP*2048*80 = 1,310,720
  float* ki   = ws + 1310720;               // 131072
  float* wgt  = ws + 1441792;               // 32768
  float* qi   = ws + 1474560;               // 2,097,152
  float* qe   = ws + 3571712;               // 131072
  float* sc   = ws + 3702784;               // 4,194,304
  int*   idx  = (int*)(ws + 7897088);       // 262144 ints
  int*   cnt  = (int*)(ws + 8159232);       // 2048 ints
  // f16 K/V reuse the part region (dead after k_lnw)
  unsigned short* kh = (unsigned short*)part;
  unsigned short* vh = kh + (size_t)S * NH * 64;
  // split-bf16 staging for qi GEMM reuses sc region (dead until k_scores)
  unsigned short* Ah = (unsigned short*)sc;
  unsigned short* Al = Ah + (size_t)S * QIN;
  unsigned short* Bh = Al + (size_t)S * QIN;
  unsigned short* Bl = Bh + (size_t)1024 * QIN;

  hipLaunchKernelGGL(k_part,    dim3(KP, 32), dim3(256), 0, stream, x, wk, ww, part);
  hipLaunchKernelGGL(k_lnw,     dim3(512),    dim3(256), 0, stream, part, lng, lnb, ki, wgt);
  hipLaunchKernelGGL(k_prep,    dim3(3584),   dim3(256), 0, stream, qin, Ah, Al, k, kh, v, vh, wq, Bh, Bl);
  hipLaunchKernelGGL(k_qi_mfma, dim3(16, 32), dim3(256), 0, stream, Ah, Al, Bh, Bl, qi);
  hipLaunchKernelGGL(k_qeff,    dim3(512),    dim3(256), 0, stream, qi, wgt, qe);
  hipLaunchKernelGGL(k_scores,  dim3(32, 32), dim3(256), 0, stream, qe, ki, sc);
  hipLaunchKernelGGL(k_topk,    dim3(2048),   dim3(256), 0, stream, sc, idx, cnt);
  hipLaunchKernelGGL(k_attn,    dim3(2048),   dim3(256), 0, stream, q, kh, vh, idx, cnt, out);
}

// Round 8
// 113.657 us; speedup vs baseline: 2.8807x; 1.0570x over previous
//
#include <hip/hip_runtime.h>
#include <hip/hip_bf16.h>
#include <hip/hip_fp16.h>
#include <math.h>

#define S 2048
#define DM 1024
#define QIN 512
#define HI 16
#define DI 64
#define NH 8
#define TOPK 128
#define LN_EPS 1e-5f
#define KP 8   // k_part split-K factor

typedef float f32x4 __attribute__((ext_vector_type(4)));
typedef short s16x8 __attribute__((ext_vector_type(8)));

__device__ __forceinline__ float wave_sum(float v){
#pragma unroll
  for (int o = 32; o; o >>= 1) v += __shfl_xor(v, o);
  return v;
}
__device__ __forceinline__ float wave_max(float v){
#pragma unroll
  for (int o = 32; o; o >>= 1) v = fmaxf(v, __shfl_xor(v, o));
  return v;
}
__device__ __forceinline__ unsigned short f2bf(float x){
  unsigned u = __float_as_uint(x);
  unsigned r = u + 0x7FFFu + ((u >> 16) & 1u);   // RN-even
  return (unsigned short)(r >> 16);
}
__device__ __forceinline__ float bf2f(unsigned short s){
  return __uint_as_float(((unsigned)s) << 16);
}
__device__ __forceinline__ unsigned short f2h(float x){
  return __half_as_ushort(__float2half_rn(x));
}
union UH2 { unsigned int u; __half2 h; };
__device__ __forceinline__ __half2 as_half2(unsigned int u){ UH2 x; x.u = u; return x.h; }

// ======== F1: fused [k_part (256 blocks) | prep-convert (3072) | trsplit (512)] ========
__global__ __launch_bounds__(256) void k_f1(const float* __restrict__ x,
                                            const float* __restrict__ wk,
                                            const float* __restrict__ ww,
                                            float* __restrict__ part,
                                            const float* __restrict__ qin,
                                            unsigned short* __restrict__ Ah,
                                            unsigned short* __restrict__ Al,
                                            const float* __restrict__ k,
                                            unsigned short* __restrict__ kh,
                                            const float* __restrict__ v,
                                            unsigned short* __restrict__ vh,
                                            const float* __restrict__ wq,
                                            unsigned short* __restrict__ Bh,
                                            unsigned short* __restrict__ Bl){
  __shared__ float As[32][68];
  __shared__ float Bs[32][84];
  const int bid = blockIdx.x;
  const int t = threadIdx.x;

  if (bid < 256){
    // ---- k_part: split-K partial GEMM x(2048x1024) @ [wk|ww](1024x80) ----
    const int kp = bid & 7;       // 0..KP-1
    const int bm = bid >> 3;      // 0..31
    const int m0 = bm * 64;
    const int tm = (t & 15) * 4;
    const int tn = (t >> 4) * 5;
    float acc[4][5];
#pragma unroll
    for (int i = 0; i < 4; i++)
#pragma unroll
      for (int j = 0; j < 5; j++) acc[i][j] = 0.f;

    for (int kb = 0; kb < (DM / KP) / 32; ++kb){
      const int k0 = kp * (DM / KP) + kb * 32;
#pragma unroll
      for (int i = 0; i < 2; i++){
        int u = t + i * 256;
        int m = u >> 3, c4 = u & 7;
        float4 a = *(const float4*)&x[(size_t)(m0 + m) * DM + k0 + c4 * 4];
        As[c4*4+0][m] = a.x; As[c4*4+1][m] = a.y; As[c4*4+2][m] = a.z; As[c4*4+3][m] = a.w;
      }
#pragma unroll
      for (int i = 0; i < 10; i++){
        int u = t + i * 256;
        int kk = u / 80, nn = u % 80;
        float val = (nn < 64) ? wk[(size_t)(k0 + kk) * 64 + nn]
                              : ww[(size_t)(k0 + kk) * 16 + (nn - 64)];
        Bs[kk][nn] = val;
      }
      __syncthreads();
#pragma unroll
      for (int kk = 0; kk < 32; ++kk){
        float4 a = *(const float4*)&As[kk][tm];
        float av[4] = {a.x, a.y, a.z, a.w};
        float bb[5];
#pragma unroll
        for (int j = 0; j < 5; j++) bb[j] = Bs[kk][tn + j];
#pragma unroll
        for (int i = 0; i < 4; i++)
#pragma unroll
          for (int j = 0; j < 5; j++) acc[i][j] = fmaf(av[i], bb[j], acc[i][j]);
      }
      __syncthreads();
    }
    float* dst = part + (size_t)kp * S * 80;
#pragma unroll
    for (int i = 0; i < 4; i++)
#pragma unroll
      for (int j = 0; j < 5; j++)
        dst[(size_t)(m0 + tm + i) * 80 + tn + j] = acc[i][j];
    return;
  }

  if (bid < 256 + 3072){
    // ---- prep-convert: split-bf16(q_input), f16(K), f16(V) ----
    const int SEG0 = S * QIN / 4;      // 262144
    const int SEG1 = S * NH * 64 / 4;  // 262144
    int id = (bid - 256) * 256 + t;
    if (id < SEG0){
      float4 f = ((const float4*)qin)[id];
      ushort4 h, lo;
      h.x = f2bf(f.x); lo.x = f2bf(f.x - bf2f(h.x));
      h.y = f2bf(f.y); lo.y = f2bf(f.y - bf2f(h.y));
      h.z = f2bf(f.z); lo.z = f2bf(f.z - bf2f(h.z));
      h.w = f2bf(f.w); lo.w = f2bf(f.w - bf2f(h.w));
      ((ushort4*)Ah)[id] = h;
      ((ushort4*)Al)[id] = lo;
    } else if (id < SEG0 + SEG1){
      int j = id - SEG0;
      float4 f = ((const float4*)k)[j];
      ushort4 o;
      o.x = f2h(f.x); o.y = f2h(f.y); o.z = f2h(f.z); o.w = f2h(f.w);
      ((ushort4*)kh)[j] = o;
    } else {
      int j = id - SEG0 - SEG1;
      float4 f = ((const float4*)v)[j];
      ushort4 o;
      o.x = f2h(f.x); o.y = f2h(f.y); o.z = f2h(f.z); o.w = f2h(f.w);
      ((ushort4*)vh)[j] = o;
    }
    return;
  }

  // ---- trsplit: w_q (512x1024) -> transposed split bf16 [n][k] hi/lo ----
  {
    unsigned short (*lh)[33] = (unsigned short(*)[33])&As[0][0];
    unsigned short (*ll)[33] = (unsigned short(*)[33])&Bs[0][0];
    const int b2 = bid - 3328;          // 0..511
    const int k0 = (b2 & 15) * 32;
    const int n0 = (b2 >> 4) * 32;
    const int c = t & 31, r8 = t >> 5;
#pragma unroll
    for (int i = 0; i < 4; ++i){
      int kk = r8 + i * 8;
      float wv = wq[(size_t)(k0 + kk) * 1024 + n0 + c];
      unsigned short h = f2bf(wv);
      lh[c][kk] = h;
      ll[c][kk] = f2bf(wv - bf2f(h));
    }
    __syncthreads();
    const int kk = t & 31, nl = t >> 5;
#pragma unroll
    for (int i = 0; i < 4; ++i){
      int nn = nl + i * 8;
      Bh[(size_t)(n0 + nn) * QIN + k0 + kk] = lh[nn][kk];
      Bl[(size_t)(n0 + nn) * QIN + k0 + kk] = ll[nn][kk];
    }
  }
}

// ======== F2: fused [k_lnw (512 blocks) | k_qi_mfma (512 blocks)] ========
__global__ __launch_bounds__(256) void k_f2(const float* __restrict__ part,
                                            const float* __restrict__ g,
                                            const float* __restrict__ b,
                                            float* __restrict__ ki,
                                            float* __restrict__ wgt,
                                            const unsigned short* __restrict__ Ah,
                                            const unsigned short* __restrict__ Al,
                                            const unsigned short* __restrict__ Bh,
                                            const unsigned short* __restrict__ Bl,
                                            float* __restrict__ qi){
  const int bid = blockIdx.x;
  if (bid < 512){
    // ---- lnw: reduce split-K partials, LayerNorm(ki), scale wgt (4 rows/block) ----
    const int s = bid * 4 + (threadIdx.x >> 6);
    const int l = threadIdx.x & 63;
    float kv = 0.f;
#pragma unroll
    for (int p = 0; p < KP; p++) kv += part[(size_t)p * S * 80 + (size_t)s * 80 + l];
    float wv = 0.f;
    if (l < 16){
#pragma unroll
      for (int p = 0; p < KP; p++) wv += part[(size_t)p * S * 80 + (size_t)s * 80 + 64 + l];
    }
    float mu = wave_sum(kv) * (1.f / 64.f);
    float d  = kv - mu;
    float var = wave_sum(d * d) * (1.f / 64.f);
    float o = d * (1.f / sqrtf(var + LN_EPS)) * g[l] + b[l];
    ki[(size_t)s * 64 + l] = o;
    if (l < 16) wgt[(size_t)s * 16 + l] = wv * 0.25f;   // HI^-0.5
    return;
  }
  // ---- qi_mfma: qi = q_input @ w_q via split-bf16 MFMA (AhBh + AhBl + AlBh) ----
  const int b2 = bid - 512;
  const int bn = b2 & 15;
  const int bm = b2 >> 4;
  const int w = threadIdx.x >> 6, l = threadIdx.x & 63;
  const int m0 = bm * 64 + (w >> 1) * 32;
  const int n0 = bn * 64 + (w & 1) * 32;
  const int r = l & 15, kg = l >> 4;

  f32x4 acc00 = {0,0,0,0}, acc01 = {0,0,0,0}, acc10 = {0,0,0,0}, acc11 = {0,0,0,0};

  const size_t aoff = (size_t)(m0 + r) * QIN + kg * 8;
  const size_t boff = (size_t)(n0 + r) * QIN + kg * 8;
#pragma unroll 4
  for (int k0 = 0; k0 < QIN; k0 += 32){
    s16x8 ah0 = *(const s16x8*)(Ah + aoff + k0);
    s16x8 ah1 = *(const s16x8*)(Ah + aoff + 16 * QIN + k0);
    s16x8 al0 = *(const s16x8*)(Al + aoff + k0);
    s16x8 al1 = *(const s16x8*)(Al + aoff + 16 * QIN + k0);
    s16x8 bh0 = *(const s16x8*)(Bh + boff + k0);
    s16x8 bh1 = *(const s16x8*)(Bh + boff + 16 * QIN + k0);
    s16x8 bl0 = *(const s16x8*)(Bl + boff + k0);
    s16x8 bl1 = *(const s16x8*)(Bl + boff + 16 * QIN + k0);
    acc00 = __builtin_amdgcn_mfma_f32_16x16x32_bf16(ah0, bh0, acc00, 0, 0, 0);
    acc00 = __builtin_amdgcn_mfma_f32_16x16x32_bf16(ah0, bl0, acc00, 0, 0, 0);
    acc00 = __builtin_amdgcn_mfma_f32_16x16x32_bf16(al0, bh0, acc00, 0, 0, 0);
    acc01 = __builtin_amdgcn_mfma_f32_16x16x32_bf16(ah0, bh1, acc01, 0, 0, 0);
    acc01 = __builtin_amdgcn_mfma_f32_16x16x32_bf16(ah0, bl1, acc01, 0, 0, 0);
    acc01 = __builtin_amdgcn_mfma_f32_16x16x32_bf16(al0, bh1, acc01, 0, 0, 0);
    acc10 = __builtin_amdgcn_mfma_f32_16x16x32_bf16(ah1, bh0, acc10, 0, 0, 0);
    acc10 = __builtin_amdgcn_mfma_f32_16x16x32_bf16(ah1, bl0, acc10, 0, 0, 0);
    acc10 = __builtin_amdgcn_mfma_f32_16x16x32_bf16(al1, bh0, acc10, 0, 0, 0);
    acc11 = __builtin_amdgcn_mfma_f32_16x16x32_bf16(ah1, bh1, acc11, 0, 0, 0);
    acc11 = __builtin_amdgcn_mfma_f32_16x16x32_bf16(ah1, bl1, acc11, 0, 0, 0);
    acc11 = __builtin_amdgcn_mfma_f32_16x16x32_bf16(al1, bh1, acc11, 0, 0, 0);
  }
  // C layout: col = lane&15, row = (lane>>4)*4 + j
#pragma unroll
  for (int j = 0; j < 4; ++j){
    qi[(size_t)(m0 +  0 + kg * 4 + j) * 1024 + n0 +  0 + r] = acc00[j];
    qi[(size_t)(m0 +  0 + kg * 4 + j) * 1024 + n0 + 16 + r] = acc01[j];
    qi[(size_t)(m0 + 16 + kg * 4 + j) * 1024 + n0 +  0 + r] = acc10[j];
    qi[(size_t)(m0 + 16 + kg * 4 + j) * 1024 + n0 + 16 + r] = acc11[j];
  }
}

// ---------------- kernel 4: q_eff[s,d] = DI^-0.5 * sum_h wgt[s,h]*qi[s,h*64+d] ----------------
__global__ __launch_bounds__(256) void k_qeff(const float* __restrict__ qi,
                                              const float* __restrict__ wgt,
                                              float* __restrict__ qe){
  const int id = blockIdx.x * 256 + threadIdx.x;  // S*64 total
  const int s = id >> 6, d = id & 63;
  float acc = 0.f;
#pragma unroll
  for (int h = 0; h < 16; h++)
    acc = fmaf(wgt[(size_t)s * 16 + h], qi[(size_t)s * 1024 + h * 64 + d], acc);
  qe[(size_t)s * 64 + d] = acc * 0.125f;   // DI^-0.5
}

// ---------------- kernel 5: scores[i,j] = q_eff[i] . ki[j]  (lower-triangular tiles only) ----------------
__global__ __launch_bounds__(256) void k_scores(const float* __restrict__ qe,
                                                const float* __restrict__ ki,
                                                float* __restrict__ sc){
  const int bj = blockIdx.x, bi = blockIdx.y;
  if (bj > bi) return;
  const int t = threadIdx.x;
  const int i0 = bi * 64, j0 = bj * 64;
  __shared__ float Qs[64][68];  // [d][i]
  __shared__ float Ks[64][68];  // [d][j]
#pragma unroll
  for (int u0 = 0; u0 < 4; ++u0){
    int u = t + u0 * 256;
    int r = u >> 4, d4 = u & 15;
    float4 a = *(const float4*)&qe[(size_t)(i0 + r) * 64 + d4 * 4];
    Qs[d4*4+0][r] = a.x; Qs[d4*4+1][r] = a.y; Qs[d4*4+2][r] = a.z; Qs[d4*4+3][r] = a.w;
    float4 b = *(const float4*)&ki[(size_t)(j0 + r) * 64 + d4 * 4];
    Ks[d4*4+0][r] = b.x; Ks[d4*4+1][r] = b.y; Ks[d4*4+2][r] = b.z; Ks[d4*4+3][r] = b.w;
  }
  __syncthreads();
  const int tm = (t & 15) * 4, tn = (t >> 4) * 4;
  float acc[4][4] = {};
#pragma unroll
  for (int d = 0; d < 64; ++d){
    float4 a = *(const float4*)&Qs[d][tm];
    float4 b = *(const float4*)&Ks[d][tn];
    float av[4] = {a.x, a.y, a.z, a.w}, bb[4] = {b.x, b.y, b.z, b.w};
#pragma unroll
    for (int i = 0; i < 4; i++)
#pragma unroll
      for (int j = 0; j < 4; j++) acc[i][j] = fmaf(av[i], bb[j], acc[i][j]);
  }
#pragma unroll
  for (int i = 0; i < 4; i++)
#pragma unroll
    for (int j = 0; j < 4; j++)
      sc[(size_t)(i0 + tm + i) * S + j0 + tn + j] = acc[i][j];
}

// ---------------- kernel 6: per-row causal top-128 — radix select with candidate compaction ----------------
__global__ __launch_bounds__(256) void k_topk(const float* __restrict__ sc,
                                              int* __restrict__ idx,
                                              int* __restrict__ cnt){
  const int i = blockIdx.x, t = threadIdx.x;
  const int w = t >> 6, l = t & 63;
  const int n = i + 1;           // valid causal candidates
  int* outr = idx + (size_t)i * TOPK;
  if (n <= TOPK){
    for (int m = t; m < n; m += 256) outr[m] = m;
    if (t == 0) cnt[i] = n;
    return;
  }
  __shared__ unsigned int keys[S];
  __shared__ int lA[S];
  __shared__ int lB[S];
  __shared__ int hist[256];
  __shared__ int wtot[4];
  __shared__ int s_b, s_above, s_out, s_m;
  hist[t] = 0;
  if (t == 0) s_out = 0;
  __syncthreads();
  for (int j = t; j < n; j += 256){
    unsigned int u = __float_as_uint(sc[(size_t)i * S + j]);
    unsigned int kk = (u & 0x80000000u) ? ~u : (u | 0x80000000u);   // order-preserving key
    keys[j] = kk;
    atomicAdd(&hist[kk >> 24], 1);    // top-byte histogram fused into load
  }
  __syncthreads();
  int rem = TOPK;
  // ---- pass 3: pick top-byte boundary bucket ----
  {
    const int h = hist[t];
    int vsc = h;
#pragma unroll
    for (int off = 1; off < 64; off <<= 1){
      int u = __shfl_down(vsc, off);
      if (l + off < 64) vsc += u;
    }
    if (l == 0) wtot[w] = vsc;
    __syncthreads();
    int later = 0;
#pragma unroll
    for (int ww = 1; ww < 4; ++ww) if (ww > w) later += wtot[ww];
    const int excl = vsc + later - h;
    if (excl < rem && excl + h >= rem){ s_b = t; s_above = excl; }
    __syncthreads();
  }
  int b = s_b;
  rem -= s_above;
  if (t == 0) s_m = 0;
  __syncthreads();
  // ---- single pass: emit definite-ins, compact boundary bucket ----
  for (int j = t; j < n; j += 256){
    int by = keys[j] >> 24;
    if (by > b){ int p = atomicAdd(&s_out, 1); outr[p] = j; }
    else if (by == b){ int p = atomicAdd(&s_m, 1); lA[p] = j; }
  }
  __syncthreads();
  int m = s_m;
  int* Lsrc = lA; int* Ldst = lB;
  bool done = false;
  if (m == rem){
    int base = TOPK - rem;
    for (int u = t; u < m; u += 256) outr[base + u] = Lsrc[u];
    done = true;
  }
  // ---- refine on compacted list (typically 30-300 entries) ----
  for (int p = 2; p >= 0 && !done; --p){
    const int sh = p * 8;
    __syncthreads();
    hist[t] = 0;
    __syncthreads();
    for (int u = t; u < m; u += 256) atomicAdd(&hist[(keys[Lsrc[u]] >> sh) & 255], 1);
    __syncthreads();
    {
      const int h = hist[t];
      int vsc = h;
#pragma unroll
      for (int off = 1; off < 64; off <<= 1){
        int u = __shfl_down(vsc, off);
        if (l + off < 64) vsc += u;
      }
      if (l == 0) wtot[w] = vsc;
      __syncthreads();
      int later = 0;
#pragma unroll
      for (int ww = 1; ww < 4; ++ww) if (ww > w) later += wtot[ww];
      const int excl = vsc + later - h;
      if (excl < rem && excl + h >= rem){ s_b = t; s_above = excl; }
      __syncthreads();
    }
    b = s_b;
    rem -= s_above;
    if (t == 0) s_m = 0;
    __syncthreads();
    for (int u = t; u < m; u += 256){
      int j = Lsrc[u]; int by = (keys[j] >> sh) & 255;
      if (by > b){ int p2 = atomicAdd(&s_out, 1); outr[p2] = j; }
      else if (by == b){ int p2 = atomicAdd(&s_m, 1); Ldst[p2] = j; }
    }
    __syncthreads();
    m = s_m;
    { int* tmp = Lsrc; Lsrc = Ldst; Ldst = tmp; }
    if (m == rem){
      int base = TOPK - rem;
      for (int u = t; u < m; u += 256) outr[base + u] = Lsrc[u];
      done = true;
    }
  }
  if (!done && t == 0){
    // exact 32-bit ties: take rem lowest indices (rare)
    int base = TOPK - rem;
    for (int a = 0; a < rem; ++a){
      int mn = 1 << 30, pos = -1;
      for (int u = 0; u < m; ++u){ int j = Lsrc[u]; if (j < mn){ mn = j; pos = u; } }
      outr[base + a] = mn; Lsrc[pos] = 1 << 30;
    }
  }
  if (t == 0) cnt[i] = TOPK;
}

// ---------------- kernel 7: gathered sparse attention — f16 K/V, 16B/lane PV, barrier-free ----------------
__global__ __launch_bounds__(256) void k_attn(const float* __restrict__ q,
                                              const unsigned short* __restrict__ kh,
                                              const unsigned short* __restrict__ vh,
                                              const int* __restrict__ idx,
                                              const int* __restrict__ cnt,
                                              float* __restrict__ out){
  const int i = blockIdx.x;
  const int w = threadIdx.x >> 6, l = threadIdx.x & 63;
  const int n = cnt[i];
  const int* irow = idx + (size_t)i * TOPK;

  __shared__ int   sidx[4][TOPK];      // per-wave private copies -> no __syncthreads
  __shared__ float sp[4][2][TOPK];

  sidx[w][l]      = (l < n)      ? irow[l]      : 0;
  sidx[w][l + 64] = (l + 64 < n) ? irow[l + 64] : 0;

  const int h0 = 2 * w, h1 = h0 + 1;
  const int g = l >> 3, gl = l & 7;
  const float* qrow = q + (size_t)i * (NH * 64);
  __half2 qa2[4], qb2[4];
  {
    float4 a0 = *(const float4*)&qrow[h0 * 64 + gl * 8];
    float4 a1 = *(const float4*)&qrow[h0 * 64 + gl * 8 + 4];
    float4 b0 = *(const float4*)&qrow[h1 * 64 + gl * 8];
    float4 b1 = *(const float4*)&qrow[h1 * 64 + gl * 8 + 4];
    qa2[0] = __floats2half2_rn(a0.x * 0.125f, a0.y * 0.125f);
    qa2[1] = __floats2half2_rn(a0.z * 0.125f, a0.w * 0.125f);
    qa2[2] = __floats2half2_rn(a1.x * 0.125f, a1.y * 0.125f);
    qa2[3] = __floats2half2_rn(a1.z * 0.125f, a1.w * 0.125f);
    qb2[0] = __floats2half2_rn(b0.x * 0.125f, b0.y * 0.125f);
    qb2[1] = __floats2half2_rn(b0.z * 0.125f, b0.w * 0.125f);
    qb2[2] = __floats2half2_rn(b1.x * 0.125f, b1.y * 0.125f);
    qb2[3] = __floats2half2_rn(b1.z * 0.125f, b1.w * 0.125f);
  }
  asm volatile("" ::: "memory");

  // ---- QK: 8-lane groups; group g handles key j=pass*8+g; lane covers 8 dims via packed f16 fma ----
#pragma unroll 4
  for (int pass = 0; pass < TOPK / 8; ++pass){
    const int j = pass * 8 + g;
    const size_t base = (size_t)sidx[w][j] * (NH * 64);
    uint4 u0 = *(const uint4*)(kh + base + h0 * 64 + gl * 8);
    uint4 u1 = *(const uint4*)(kh + base + h1 * 64 + gl * 8);
    __half2 acc0 = __floats2half2_rn(0.f, 0.f);
    __half2 acc1 = __floats2half2_rn(0.f, 0.f);
    acc0 = __hfma2(as_half2(u0.x), qa2[0], acc0);
    acc0 = __hfma2(as_half2(u0.y), qa2[1], acc0);
    acc0 = __hfma2(as_half2(u0.z), qa2[2], acc0);
    acc0 = __hfma2(as_half2(u0.w), qa2[3], acc0);
    acc1 = __hfma2(as_half2(u1.x), qb2[0], acc1);
    acc1 = __hfma2(as_half2(u1.y), qb2[1], acc1);
    acc1 = __hfma2(as_half2(u1.z), qb2[2], acc1);
    acc1 = __hfma2(as_half2(u1.w), qb2[3], acc1);
    float d0 = __low2float(acc0) + __high2float(acc0);
    float d1 = __low2float(acc1) + __high2float(acc1);
#pragma unroll
    for (int o = 1; o < 8; o <<= 1){ d0 += __shfl_xor(d0, o); d1 += __shfl_xor(d1, o); }
    if (gl == 0){ sp[w][0][j] = d0; sp[w][1][j] = d1; }
  }
  asm volatile("" ::: "memory");

  // ---- softmax per head across the wave (2 entries per lane); all wave-local ----
  const bool v0 = (l < n), v1 = (l + 64 < n);
  {
    float s0 = v0 ? sp[w][0][l] : -1e30f, s1 = v1 ? sp[w][0][l + 64] : -1e30f;
    float m = wave_max(fmaxf(s0, s1));
    float e0 = v0 ? __expf(s0 - m) : 0.f;
    float e1 = v1 ? __expf(s1 - m) : 0.f;
    float inv = 1.f / wave_sum(e0 + e1);
    sp[w][0][l] = e0 * inv;
    sp[w][0][l + 64] = e1 * inv;
  }
  {
    float s0 = v0 ? sp[w][1][l] : -1e30f, s1 = v1 ? sp[w][1][l + 64] : -1e30f;
    float m = wave_max(fmaxf(s0, s1));
    float e0 = v0 ? __expf(s0 - m) : 0.f;
    float e1 = v1 ? __expf(s1 - m) : 0.f;
    float inv = 1.f / wave_sum(e0 + e1);
    sp[w][1][l] = e0 * inv;
    sp[w][1][l + 64] = e1 * inv;
  }
  asm volatile("" ::: "memory");

  // ---- PV: 16B/lane — one wave-load covers 4 keys x 2 heads (8 dims/lane) ----
  const int kq = l >> 4;               // 0..3 key slot
  const int hp = (l >> 3) & 1;         // head parity within wave
  const int d8 = (l & 7) * 8;          // 8 dims per lane
  float o8[8] = {0,0,0,0,0,0,0,0};
#pragma unroll 4
  for (int pass = 0; pass < TOPK / 4; ++pass){
    const int j = pass * 4 + kq;
    const size_t base = (size_t)sidx[w][j] * (NH * 64);
    uint4 uv = *(const uint4*)(vh + base + (h0 + hp) * 64 + d8);
    float p = sp[w][hp][j];
    __half2 va = as_half2(uv.x), vb = as_half2(uv.y), vc = as_half2(uv.z), vd = as_half2(uv.w);
    o8[0] = fmaf(p, __low2float(va),  o8[0]);
    o8[1] = fmaf(p, __high2float(va), o8[1]);
    o8[2] = fmaf(p, __low2float(vb),  o8[2]);
    o8[3] = fmaf(p, __high2float(vb), o8[3]);
    o8[4] = fmaf(p, __low2float(vc),  o8[4]);
    o8[5] = fmaf(p, __high2float(vc), o8[5]);
    o8[6] = fmaf(p, __low2float(vd),  o8[6]);
    o8[7] = fmaf(p, __high2float(vd), o8[7]);
  }
#pragma unroll
  for (int e = 0; e < 8; ++e){
    o8[e] += __shfl_xor(o8[e], 16);
    o8[e] += __shfl_xor(o8[e], 32);
  }
  if (l < 16){
    float* dst = &out[(size_t)i * (NH * 64) + (h0 + hp) * 64 + d8];
    *(float4*)dst       = make_float4(o8[0], o8[1], o8[2], o8[3]);
    *(float4*)(dst + 4) = make_float4(o8[4], o8[5], o8[6], o8[7]);
  }
}

extern "C" void kernel_launch(void* const* d_in, const int* in_sizes, int n_in,
                              void* d_out, int out_size, void* d_ws, size_t ws_size,
                              hipStream_t stream){
  const float* x   = (const float*)d_in[0];
  const float* qin = (const float*)d_in[1];
  const float* q   = (const float*)d_in[2];
  const float* k   = (const float*)d_in[3];
  const float* v   = (const float*)d_in[4];
  const float* wq  = (const float*)d_in[5];
  const float* wk  = (const float*)d_in[6];
  const float* lng = (const float*)d_in[7];
  const float* lnb = (const float*)d_in[8];
  const float* ww  = (const float*)d_in[9];
  float* out = (float*)d_out;

  float* ws   = (float*)d_ws;
  float* part = ws;                         // KP*2048*80 = 1,310,720
  float* ki   = ws + 1310720;               // 131072
  float* wgt  = ws + 1441792;               // 32768
  float* qi   = ws + 1474560;               // 2,097,152
  float* qe   = ws + 3571712;               // 131072
  float* sc   = ws + 3702784;               // 4,194,304
  int*   idx  = (int*)(ws + 7897088);       // 262144 ints
  int*   cnt  = (int*)(ws + 8159232);       // 2048 ints
  // f16 K/V: OWN region (must not alias part — written concurrently in F1)
  unsigned short* kh = (unsigned short*)(ws + 8161280);   // 1,048,576 ushorts
  unsigned short* vh = kh + (size_t)S * NH * 64;          // 1,048,576 ushorts
  // split-bf16 staging for qi GEMM reuses sc region (dead until k_scores)
  unsigned short* Ah = (unsigned short*)sc;
  unsigned short* Al = Ah + (size_t)S * QIN;
  unsigned short* Bh = Al + (size_t)S * QIN;
  unsigned short* Bl = Bh + (size_t)1024 * QIN;

  hipLaunchKernelGGL(k_f1,     dim3(3840),   dim3(256), 0, stream,
                     x, wk, ww, part, qin, Ah, Al, k, kh, v, vh, wq, Bh, Bl);
  hipLaunchKernelGGL(k_f2,     dim3(1024),   dim3(256), 0, stream,
                     part, lng, lnb, ki, wgt, Ah, Al, Bh, Bl, qi);
  hipLaunchKernelGGL(k_qeff,   dim3(512),    dim3(256), 0, stream, qi, wgt, qe);
  hipLaunchKernelGGL(k_scores, dim3(32, 32), dim3(256), 0, stream, qe, ki, sc);
  hipLaunchKernelGGL(k_topk,   dim3(2048),   dim3(256), 0, stream, sc, idx, cnt);
  hipLaunchKernelGGL(k_attn,   dim3(2048),   dim3(256), 0, stream, q, kh, vh, idx, cnt, out);
}